// Round 1
// baseline (1037.303 us; speedup 1.0000x reference)
//
#include <hip/hip_runtime.h>
#include <math.h>

// Problem constants (B=4, S=1024, HIDDEN=4096, H=32, KV=8, D=128)
#define SEQ    1024
#define BATCH  4
#define MROWS  4096          // B*S
#define HID    4096
#define NHEADS 32
#define NKV    8
#define HDIM   128

typedef __bf16 bf16x8 __attribute__((ext_vector_type(8)));
typedef float  f32x4  __attribute__((ext_vector_type(4)));
typedef unsigned short u16x8 __attribute__((ext_vector_type(8)));
typedef unsigned short u16x4 __attribute__((ext_vector_type(4)));

static __device__ __forceinline__ unsigned short f2bf(float f) {
  union { float f; unsigned u; } x; x.f = f;
  unsigned r = x.u + 0x7fffu + ((x.u >> 16) & 1u);   // RNE
  return (unsigned short)(r >> 16);
}
static __device__ __forceinline__ float bf2f(unsigned short h) {
  union { unsigned u; float f; } x; x.u = ((unsigned)h) << 16;
  return x.f;
}

// async global->LDS, 16B per lane; LDS dest is wave-uniform base + lane*16
static __device__ __forceinline__ void gload16(const unsigned short* g, unsigned short* l) {
  __builtin_amdgcn_global_load_lds(
      (const __attribute__((address_space(1))) unsigned int*)g,
      (__attribute__((address_space(3))) unsigned int*)l, 16, 0, 0);
}

// ---------------------------------------------------------------- f32 -> bf16
__global__ __launch_bounds__(256) void cvt_kernel(const float* __restrict__ in,
                                                  unsigned short* __restrict__ out,
                                                  int n8) {
  int i = blockIdx.x * 256 + threadIdx.x;
  if (i >= n8) return;
  f32x4 a = ((const f32x4*)in)[2 * i];
  f32x4 b = ((const f32x4*)in)[2 * i + 1];
  u16x8 o;
  o[0] = f2bf(a[0]); o[1] = f2bf(a[1]); o[2] = f2bf(a[2]); o[3] = f2bf(a[3]);
  o[4] = f2bf(b[0]); o[5] = f2bf(b[1]); o[6] = f2bf(b[2]); o[7] = f2bf(b[3]);
  ((u16x8*)out)[i] = o;
}

// ------------------------------------------------------- C = A * B^T (bf16 MFMA)
// A: [M][K] bf16 row-major, B: [N][K] bf16 row-major (K contiguous both).
// OUTMODE: 0 = bf16 C[M][N] (ldc=N), 1 = f32 C[M][N] (ldc=N),
//          2 = bf16 C^T[N][M] (ldc=M).
// 128x128 tile, 4 waves (2x2 of 64x64), BK=32, single-buffered LDS,
// global_load_lds staging with k-group XOR swizzle (pre-swizzled global src).
template <int OUTMODE>
__global__ __launch_bounds__(256) void gemm_bt(const unsigned short* __restrict__ A,
                                               const unsigned short* __restrict__ B,
                                               void* __restrict__ Cp,
                                               int M, int N, int K, int ldc) {
  __shared__ unsigned short As[4096];   // [128][32]
  __shared__ unsigned short Bs[4096];
  const int t  = threadIdx.x;
  const int l  = t & 63, w = t >> 6;
  const int wr = w >> 1, wc = w & 1;
  const int lr = l & 15, lg = l >> 4;
  const int m0 = blockIdx.y * 128, n0 = blockIdx.x * 128;

  // staging: thread t owns LDS slot (row=t>>2, kslot=t&3); data k-group is
  // swizzled: kg_data = kslot ^ (row&3)  (bank-conflict fix, both-sides)
  const int srow = t >> 2;
  const int skg  = (t & 3) ^ (srow & 3);
  const unsigned short* ga0 = A + (long)(m0 + srow) * K + skg * 8;
  const unsigned short* ga1 = ga0 + 64L * K;
  const unsigned short* gb0 = B + (long)(n0 + srow) * K + skg * 8;
  const unsigned short* gb1 = gb0 + 64L * K;

  // fragment read offsets (apply same XOR on read side)
  int aro[4], bro[4];
#pragma unroll
  for (int i = 0; i < 4; ++i) {
    aro[i] = (wr * 64 + i * 16 + lr) * 32 + ((lg ^ (lr & 3)) * 8);
    bro[i] = (wc * 64 + i * 16 + lr) * 32 + ((lg ^ (lr & 3)) * 8);
  }

  f32x4 acc[4][4] = {};
  for (int k0 = 0; k0 < K; k0 += 32) {
    if (k0) __syncthreads();
    gload16(ga0 + k0, As + (w << 9));
    gload16(ga1 + k0, As + 2048 + (w << 9));
    gload16(gb0 + k0, Bs + (w << 9));
    gload16(gb1 + k0, Bs + 2048 + (w << 9));
    __syncthreads();   // compiler drains vmcnt before s_barrier
    bf16x8 af[4], bfv[4];
#pragma unroll
    for (int i = 0; i < 4; ++i) af[i]  = *(const bf16x8*)(As + aro[i]);
#pragma unroll
    for (int i = 0; i < 4; ++i) bfv[i] = *(const bf16x8*)(Bs + bro[i]);
#pragma unroll
    for (int mi = 0; mi < 4; ++mi)
#pragma unroll
      for (int ni = 0; ni < 4; ++ni)
        acc[mi][ni] = __builtin_amdgcn_mfma_f32_16x16x32_bf16(af[mi], bfv[ni],
                                                              acc[mi][ni], 0, 0, 0);
  }

  // C/D layout: col = lane&15, row = (lane>>4)*4 + j   [verified m89/m91]
  const int r0 = m0 + wr * 64 + lg * 4;
  const int c0 = n0 + wc * 64 + lr;
  if (OUTMODE == 0) {
    unsigned short* C = (unsigned short*)Cp;
#pragma unroll
    for (int mi = 0; mi < 4; ++mi)
#pragma unroll
      for (int ni = 0; ni < 4; ++ni)
#pragma unroll
        for (int j = 0; j < 4; ++j)
          C[(long)(r0 + mi * 16 + j) * ldc + (c0 + ni * 16)] = f2bf(acc[mi][ni][j]);
  } else if (OUTMODE == 1) {
    float* C = (float*)Cp;
#pragma unroll
    for (int mi = 0; mi < 4; ++mi)
#pragma unroll
      for (int ni = 0; ni < 4; ++ni)
#pragma unroll
        for (int j = 0; j < 4; ++j)
          C[(long)(r0 + mi * 16 + j) * ldc + (c0 + ni * 16)] = acc[mi][ni][j];
  } else {
    unsigned short* C = (unsigned short*)Cp;   // C^T[N][M], ldc = M
#pragma unroll
    for (int mi = 0; mi < 4; ++mi)
#pragma unroll
      for (int ni = 0; ni < 4; ++ni) {
        u16x4 v;
#pragma unroll
        for (int j = 0; j < 4; ++j) v[j] = f2bf(acc[mi][ni][j]);
        *(u16x4*)(C + (long)(c0 + ni * 16) * ldc + (r0 + mi * 16)) = v;
      }
  }
}

// --------------------------------------------- fused per-head RMSNorm + RoPE
// X: bf16 [MROWS][stride], one wave per (row, head) slice of 128 elems.
// lane l owns elements l and l+64 (the RoPE rotation pair).
__global__ __launch_bounds__(256) void normrope_kernel(unsigned short* __restrict__ X,
                                                       const float* __restrict__ wnorm,
                                                       const int* __restrict__ positions,
                                                       int hshift, int stride) {
  const int t = threadIdx.x, l = t & 63, wv = t >> 6;
  const int slice = blockIdx.x * 4 + wv;
  const int head  = slice & ((1 << hshift) - 1);
  const int row   = slice >> hshift;
  const int s     = row & (SEQ - 1);
  unsigned short* p = X + (long)row * stride + (head << 7);

  float x1 = bf2f(p[l]), x2 = bf2f(p[l + 64]);
  float ss = x1 * x1 + x2 * x2;
#pragma unroll
  for (int m = 1; m < 64; m <<= 1) ss += __shfl_xor(ss, m, 64);
  float inv = rsqrtf(ss * (1.0f / 128.0f) + 1e-6f);
  x1 *= inv * wnorm[l];
  x2 *= inv * wnorm[l + 64];

  // inv_freq = ROPE_BASE^(-2l/128) = exp2(-l * log2(1e6)/64)
  float invf = exp2f((float)l * -0.31143075889569023f);
  float ang  = (float)positions[s] * invf;
  float sn, cs;
  sincosf(ang, &sn, &cs);
  p[l]      = f2bf(x1 * cs - x2 * sn);
  p[l + 64] = f2bf(x2 * cs + x1 * sn);
}

// ------------------------------------------------------------ flash attention
// Q: bf16 [4096][4096] (row=b*S+s, col=h*128+d)  (already scaled? no: scaled here)
// K: bf16 [4096][1024] (col=kv*128+d), Vt: bf16 [1024][4096] (row=kv*128+d, col=b*S+s)
// O: bf16 [4096][4096]. One wave per 16 q-rows; online softmax; no K/V staging
// (K,V per (b,kv) = 256KB each -> L2-resident; guide common-mistake #7).
__global__ __launch_bounds__(256) void attn_kernel(const unsigned short* __restrict__ Q,
                                                   const unsigned short* __restrict__ K,
                                                   const unsigned short* __restrict__ Vt,
                                                   unsigned short* __restrict__ O) {
  __shared__ unsigned short Plds[4][16][32];   // per-wave P bounce
  const int t = threadIdx.x, l = t & 63, w = t >> 6;
  const int lr = l & 15, lg = l >> 4;
  const int blk = blockIdx.x;
  const int qb = blk & 15, h = (blk >> 4) & 31, b = blk >> 9;
  const int kv = h >> 2;                     // GQA: 4 q-heads per kv-head
  const int q0 = qb * 64 + w * 16;

  // Q fragments (A-layout: row = lane&15, k = 8*(lane>>4)+j), scale folded in
  const float scale = 0.08838834764831845f;  // 1/sqrt(128)
  bf16x8 qf[4];
  const long qbase = (long)(b * SEQ + q0 + lr) * HID + h * HDIM;
#pragma unroll
  for (int kc = 0; kc < 4; ++kc) {
    u16x8 raw = *(const u16x8*)(Q + qbase + kc * 32 + lg * 8);
    bf16x8 qv;
#pragma unroll
    for (int j = 0; j < 8; ++j) qv[j] = (__bf16)(bf2f(raw[j]) * scale);
    qf[kc] = qv;
  }

  f32x4 o[8] = {};
  float mrow[4] = {-3.0e38f, -3.0e38f, -3.0e38f, -3.0e38f};
  float lsum[4] = {0.f, 0.f, 0.f, 0.f};
  const long kbase = (long)(b * SEQ) * (NKV * HDIM) + kv * HDIM;
  const long vbase = (long)(kv * HDIM) * MROWS + b * SEQ;
  const float L2E = 1.4426950408889634f;

  for (int kt = 0; kt < SEQ; kt += 32) {
    // S = Q K^T for 16 q-rows x 32 keys
    f32x4 s0 = {}, s1 = {};
#pragma unroll
    for (int kc = 0; kc < 4; ++kc) {
      bf16x8 k0v = *(const bf16x8*)(K + kbase + (long)(kt + lr) * (NKV * HDIM) + kc * 32 + lg * 8);
      bf16x8 k1v = *(const bf16x8*)(K + kbase + (long)(kt + 16 + lr) * (NKV * HDIM) + kc * 32 + lg * 8);
      s0 = __builtin_amdgcn_mfma_f32_16x16x32_bf16(qf[kc], k0v, s0, 0, 0, 0);
      s1 = __builtin_amdgcn_mfma_f32_16x16x32_bf16(qf[kc], k1v, s1, 0, 0, 0);
    }
    // online softmax (rows = lg*4+j held across the 16-lane group)
    float corr[4], pr0[4], pr1[4];
#pragma unroll
    for (int j = 0; j < 4; ++j) {
      float x = fmaxf(s0[j], s1[j]);
      x = fmaxf(x, __shfl_xor(x, 1, 64));
      x = fmaxf(x, __shfl_xor(x, 2, 64));
      x = fmaxf(x, __shfl_xor(x, 4, 64));
      x = fmaxf(x, __shfl_xor(x, 8, 64));
      float mn = fmaxf(mrow[j], x);
      corr[j] = exp2f((mrow[j] - mn) * L2E);
      mrow[j] = mn;
      pr0[j] = exp2f((s0[j] - mn) * L2E);
      pr1[j] = exp2f((s1[j] - mn) * L2E);
      float r = pr0[j] + pr1[j];
      r += __shfl_xor(r, 1, 64);
      r += __shfl_xor(r, 2, 64);
      r += __shfl_xor(r, 4, 64);
      r += __shfl_xor(r, 8, 64);
      lsum[j] = lsum[j] * corr[j] + r;
    }
#pragma unroll
    for (int nf = 0; nf < 8; ++nf)
#pragma unroll
      for (int j = 0; j < 4; ++j) o[nf][j] *= corr[j];

    // P relayout (C-layout -> A-layout) through per-wave LDS
#pragma unroll
    for (int j = 0; j < 4; ++j) {
      Plds[w][lg * 4 + j][lr]      = f2bf(pr0[j]);
      Plds[w][lg * 4 + j][16 + lr] = f2bf(pr1[j]);
    }
    bf16x8 pa = *(const bf16x8*)&Plds[w][lr][lg * 8];
    // PV: out += P (16x32) * V (32x128)
#pragma unroll
    for (int nf = 0; nf < 8; ++nf) {
      bf16x8 vf = *(const bf16x8*)(Vt + vbase + (long)(nf * 16 + lr) * MROWS + kt + lg * 8);
      o[nf] = __builtin_amdgcn_mfma_f32_16x16x32_bf16(pa, vf, o[nf], 0, 0, 0);
    }
  }

  float invl[4];
#pragma unroll
  for (int j = 0; j < 4; ++j) invl[j] = 1.0f / lsum[j];
#pragma unroll
  for (int nf = 0; nf < 8; ++nf)
#pragma unroll
    for (int j = 0; j < 4; ++j)
      O[(long)(b * SEQ + q0 + lg * 4 + j) * HID + h * HDIM + nf * 16 + lr] =
          f2bf(o[nf][j] * invl[j]);
}

// ------------------------------------------------------------------- launcher
extern "C" void kernel_launch(void* const* d_in, const int* in_sizes, int n_in,
                              void* d_out, int out_size, void* d_ws, size_t ws_size,
                              hipStream_t stream) {
  (void)in_sizes; (void)n_in; (void)out_size; (void)ws_size;
  const int*   positions = (const int*)d_in[0];
  const float* hs = (const float*)d_in[1];
  const float* wq = (const float*)d_in[2];
  const float* wk = (const float*)d_in[3];
  const float* wv = (const float*)d_in[4];
  const float* wo = (const float*)d_in[5];
  const float* qw = (const float*)d_in[6];
  const float* kw = (const float*)d_in[7];

  char* ws = (char*)d_ws;                                   // 160 MB total
  unsigned short* hs_b = (unsigned short*)(ws);              // 32 MB
  unsigned short* wq_b = (unsigned short*)(ws + 33554432);   // 32 MB (reused as attn-out)
  unsigned short* wk_b = (unsigned short*)(ws + 67108864);   //  8 MB
  unsigned short* wv_b = (unsigned short*)(ws + 75497472);   //  8 MB
  unsigned short* wo_b = (unsigned short*)(ws + 83886080);   // 32 MB
  unsigned short* q_b  = (unsigned short*)(ws + 117440512);  // 32 MB
  unsigned short* k_b  = (unsigned short*)(ws + 150994944);  //  8 MB
  unsigned short* vt_b = (unsigned short*)(ws + 159383552);  //  8 MB
  unsigned short* ao_b = wq_b;  // wq dead after Q-proj; alias for attention out

  // f32 -> bf16 conversions
  cvt_kernel<<<dim3((16777216 / 8 + 255) / 256), dim3(256), 0, stream>>>(hs, hs_b, 16777216 / 8);
  cvt_kernel<<<dim3((16777216 / 8 + 255) / 256), dim3(256), 0, stream>>>(wq, wq_b, 16777216 / 8);
  cvt_kernel<<<dim3((4194304 / 8 + 255) / 256), dim3(256), 0, stream>>>(wk, wk_b, 4194304 / 8);
  cvt_kernel<<<dim3((4194304 / 8 + 255) / 256), dim3(256), 0, stream>>>(wv, wv_b, 4194304 / 8);
  cvt_kernel<<<dim3((16777216 / 8 + 255) / 256), dim3(256), 0, stream>>>(wo, wo_b, 16777216 / 8);

  // projections
  gemm_bt<0><<<dim3(32, 32), dim3(256), 0, stream>>>(hs_b, wq_b, q_b, 4096, 4096, 4096, 4096);
  gemm_bt<0><<<dim3(8, 32), dim3(256), 0, stream>>>(hs_b, wk_b, k_b, 4096, 1024, 4096, 1024);
  gemm_bt<2><<<dim3(8, 32), dim3(256), 0, stream>>>(hs_b, wv_b, vt_b, 4096, 1024, 4096, 4096);

  // per-head RMSNorm + RoPE (in place)
  normrope_kernel<<<dim3(32768), dim3(256), 0, stream>>>(q_b, qw, positions, 5, 4096);
  normrope_kernel<<<dim3(8192), dim3(256), 0, stream>>>(k_b, kw, positions, 3, 1024);

  // attention
  attn_kernel<<<dim3(2048), dim3(256), 0, stream>>>(q_b, k_b, vt_b, ao_b);

  // output projection -> f32 d_out
  gemm_bt<1><<<dim3(32, 32), dim3(256), 0, stream>>>(ao_b, wo_b, (float*)d_out, 4096, 4096, 4096, 4096);
}

// Round 3
// 818.363 us; speedup vs baseline: 1.2675x; 1.2675x over previous
//
#include <hip/hip_runtime.h>
#include <math.h>

// Problem constants (B=4, S=1024, HIDDEN=4096, H=32, KV=8, D=128)
#define SEQ    1024
#define BATCH  4
#define MROWS  4096          // B*S
#define HID    4096
#define NHEADS 32
#define NKV    8
#define HDIM   128

typedef __bf16 bf16x8 __attribute__((ext_vector_type(8)));
typedef float  f32x4  __attribute__((ext_vector_type(4)));
typedef float  f32x16 __attribute__((ext_vector_type(16)));
typedef unsigned short u16x8 __attribute__((ext_vector_type(8)));
typedef unsigned short u16x4 __attribute__((ext_vector_type(4)));
typedef unsigned int   u32x4 __attribute__((ext_vector_type(4)));

static __device__ __forceinline__ unsigned short f2bf(float f) {
  union { float f; unsigned u; } x; x.f = f;
  unsigned r = x.u + 0x7fffu + ((x.u >> 16) & 1u);   // RNE
  return (unsigned short)(r >> 16);
}
static __device__ __forceinline__ float bf2f(unsigned short h) {
  union { unsigned u; float f; } x; x.u = ((unsigned)h) << 16;
  return x.f;
}
static __device__ __forceinline__ unsigned cvtpk_bf16(float lo, float hi) {
  unsigned r;
  asm("v_cvt_pk_bf16_f32 %0, %1, %2" : "=v"(r) : "v"(lo), "v"(hi));
  return r;
}

// async global->LDS, 16B per lane; LDS dest is wave-uniform base + lane*16
static __device__ __forceinline__ void gload16(const unsigned short* g, unsigned short* l) {
  __builtin_amdgcn_global_load_lds(
      (const __attribute__((address_space(1))) unsigned int*)g,
      (__attribute__((address_space(3))) unsigned int*)l, 16, 0, 0);
}

// ---------------------------------------------------------------- f32 -> bf16
__global__ __launch_bounds__(256) void cvt_kernel(const float* __restrict__ in,
                                                  unsigned short* __restrict__ out,
                                                  int n8) {
  int i = blockIdx.x * 256 + threadIdx.x;
  if (i >= n8) return;
  f32x4 a = ((const f32x4*)in)[2 * i];
  f32x4 b = ((const f32x4*)in)[2 * i + 1];
  u16x8 o;
  o[0] = f2bf(a[0]); o[1] = f2bf(a[1]); o[2] = f2bf(a[2]); o[3] = f2bf(a[3]);
  o[4] = f2bf(b[0]); o[5] = f2bf(b[1]); o[6] = f2bf(b[2]); o[7] = f2bf(b[3]);
  ((u16x8*)out)[i] = o;
}

// ------------------------------------------------------- C = A * B^T (bf16 MFMA)
// A: [M][K] bf16 row-major, B: [N][K] bf16 row-major (K contiguous both).
// OUTMODE: 0 = bf16 C[M][N] (ldc=N), 1 = f32 C[M][N] (ldc=N),
//          2 = bf16 C^T[N][M] (ldc=M).
template <int OUTMODE>
__global__ __launch_bounds__(256) void gemm_bt(const unsigned short* __restrict__ A,
                                               const unsigned short* __restrict__ B,
                                               void* __restrict__ Cp,
                                               int M, int N, int K, int ldc) {
  __shared__ unsigned short As[4096];   // [128][32]
  __shared__ unsigned short Bs[4096];
  const int t  = threadIdx.x;
  const int l  = t & 63, w = t >> 6;
  const int wr = w >> 1, wc = w & 1;
  const int lr = l & 15, lg = l >> 4;
  const int m0 = blockIdx.y * 128, n0 = blockIdx.x * 128;

  const int srow = t >> 2;
  const int skg  = (t & 3) ^ (srow & 3);
  const unsigned short* ga0 = A + (long)(m0 + srow) * K + skg * 8;
  const unsigned short* ga1 = ga0 + 64L * K;
  const unsigned short* gb0 = B + (long)(n0 + srow) * K + skg * 8;
  const unsigned short* gb1 = gb0 + 64L * K;

  int aro[4], bro[4];
#pragma unroll
  for (int i = 0; i < 4; ++i) {
    aro[i] = (wr * 64 + i * 16 + lr) * 32 + ((lg ^ (lr & 3)) * 8);
    bro[i] = (wc * 64 + i * 16 + lr) * 32 + ((lg ^ (lr & 3)) * 8);
  }

  f32x4 acc[4][4] = {};
  for (int k0 = 0; k0 < K; k0 += 32) {
    if (k0) __syncthreads();
    gload16(ga0 + k0, As + (w << 9));
    gload16(ga1 + k0, As + 2048 + (w << 9));
    gload16(gb0 + k0, Bs + (w << 9));
    gload16(gb1 + k0, Bs + 2048 + (w << 9));
    __syncthreads();
    bf16x8 af[4], bfv[4];
#pragma unroll
    for (int i = 0; i < 4; ++i) af[i]  = *(const bf16x8*)(As + aro[i]);
#pragma unroll
    for (int i = 0; i < 4; ++i) bfv[i] = *(const bf16x8*)(Bs + bro[i]);
#pragma unroll
    for (int mi = 0; mi < 4; ++mi)
#pragma unroll
      for (int ni = 0; ni < 4; ++ni)
        acc[mi][ni] = __builtin_amdgcn_mfma_f32_16x16x32_bf16(af[mi], bfv[ni],
                                                              acc[mi][ni], 0, 0, 0);
  }

  const int r0 = m0 + wr * 64 + lg * 4;
  const int c0 = n0 + wc * 64 + lr;
  if (OUTMODE == 0) {
    unsigned short* C = (unsigned short*)Cp;
#pragma unroll
    for (int mi = 0; mi < 4; ++mi)
#pragma unroll
      for (int ni = 0; ni < 4; ++ni)
#pragma unroll
        for (int j = 0; j < 4; ++j)
          C[(long)(r0 + mi * 16 + j) * ldc + (c0 + ni * 16)] = f2bf(acc[mi][ni][j]);
  } else if (OUTMODE == 1) {
    float* C = (float*)Cp;
#pragma unroll
    for (int mi = 0; mi < 4; ++mi)
#pragma unroll
      for (int ni = 0; ni < 4; ++ni)
#pragma unroll
        for (int j = 0; j < 4; ++j)
          C[(long)(r0 + mi * 16 + j) * ldc + (c0 + ni * 16)] = acc[mi][ni][j];
  } else {
    unsigned short* C = (unsigned short*)Cp;   // C^T[N][M], ldc = M
#pragma unroll
    for (int mi = 0; mi < 4; ++mi)
#pragma unroll
      for (int ni = 0; ni < 4; ++ni) {
        u16x4 v;
#pragma unroll
        for (int j = 0; j < 4; ++j) v[j] = f2bf(acc[mi][ni][j]);
        *(u16x4*)(C + (long)(c0 + ni * 16) * ldc + (r0 + mi * 16)) = v;
      }
  }
}

// --------------------------------------------- fused per-head RMSNorm + RoPE
__global__ __launch_bounds__(256) void normrope_kernel(unsigned short* __restrict__ X,
                                                       const float* __restrict__ wnorm,
                                                       const int* __restrict__ positions,
                                                       int hshift, int stride) {
  const int t = threadIdx.x, l = t & 63, wv = t >> 6;
  const int slice = blockIdx.x * 4 + wv;
  const int head  = slice & ((1 << hshift) - 1);
  const int row   = slice >> hshift;
  const int s     = row & (SEQ - 1);
  unsigned short* p = X + (long)row * stride + (head << 7);

  float x1 = bf2f(p[l]), x2 = bf2f(p[l + 64]);
  float ss = x1 * x1 + x2 * x2;
#pragma unroll
  for (int m = 1; m < 64; m <<= 1) ss += __shfl_xor(ss, m, 64);
  float inv = rsqrtf(ss * (1.0f / 128.0f) + 1e-6f);
  x1 *= inv * wnorm[l];
  x2 *= inv * wnorm[l + 64];

  float invf = exp2f((float)l * -0.31143075889569023f);
  float ang  = (float)positions[s] * invf;
  float sn, cs;
  sincosf(ang, &sn, &cs);
  p[l]      = f2bf(x1 * cs - x2 * sn);
  p[l + 64] = f2bf(x2 * cs + x1 * sn);
}

// ------------------------------------------------------------ flash attention
// 32x32 swapped-QK^T structure (guide §B / m214):
//   S^T = mfma_32x32x16(A=K, B=Q^T)  -> lane holds q-row (lane&31), 16 of 32 keys
//   in-register softmax (defer-max THR=8), cvt_pk + permlane32_swap P->A-frag,
//   PV = mfma_32x32x16(A=P, B=V) with V read from Vt (contiguous 16B loads).
// One wave = 32 q-rows x full D=128. 4 waves/block. No K/V LDS staging (L2-fit).
__global__ __launch_bounds__(256) void attn_kernel(const unsigned short* __restrict__ Q,
                                                   const unsigned short* __restrict__ K,
                                                   const unsigned short* __restrict__ Vt,
                                                   unsigned short* __restrict__ O) {
  __shared__ float cl[4][32];   // per-wave corr/invl transpose (P-domain -> C-domain)
  const int t = threadIdx.x, l = t & 63, w = t >> 6;
  const int lq = l & 31, hi = l >> 5;
  const int blk = blockIdx.x;
  const int qb = blk & 7, h = (blk >> 3) & 31, b = blk >> 8;
  const int kv = h >> 2;                     // GQA: 4 q-heads per kv-head
  const int q0 = qb * 128 + w * 32;

  // Q as B-fragments (col = lane&31 = q-row, k = 8*hi + j per 16-d chunk),
  // with (1/sqrt(128)) * log2(e) folded in -> softmax runs in exp2 domain.
  const float qsc = 0.12751791438584222f;
  bf16x8 qf[8];
  const unsigned short* qrow = Q + (long)(b * SEQ + q0 + lq) * HID + h * HDIM + 8 * hi;
#pragma unroll
  for (int ks = 0; ks < 8; ++ks) {
    u16x8 raw = *(const u16x8*)(qrow + ks * 16);
    bf16x8 qv;
#pragma unroll
    for (int j = 0; j < 8; ++j) qv[j] = (__bf16)(bf2f(raw[j]) * qsc);
    qf[ks] = qv;
  }

  f32x16 acc[4] = {};            // 4 d-blocks of 32 cols; rows = crow(r,hi) q-rows
  float m = -3.0e38f, lsum = 0.f;

  const unsigned short* kbase = K + (long)(b * SEQ) * (NKV * HDIM) + kv * HDIM + 8 * hi;
  const unsigned short* vbase = Vt + (long)(kv * HDIM) * MROWS + (long)b * SEQ + 8 * hi;

  for (int kt = 0; kt < SEQ; kt += 32) {
    // S^T: rows = keys, cols = q-rows. Lane holds 16 keys of q-row lq.
    f32x16 s = {};
    const unsigned short* kr = kbase + (long)(kt + lq) * (NKV * HDIM);
#pragma unroll
    for (int ks = 0; ks < 8; ++ks) {
      bf16x8 kf = *(const bf16x8*)(kr + ks * 16);
      s = __builtin_amdgcn_mfma_f32_32x32x16_bf16(kf, qf[ks], s, 0, 0, 0);
    }

    // row max over this lane's 16 keys (tree), then combine with partner half
    float t0 = fmaxf(fmaxf(s[0], s[1]), fmaxf(s[2], s[3]));
    float t1 = fmaxf(fmaxf(s[4], s[5]), fmaxf(s[6], s[7]));
    float t2 = fmaxf(fmaxf(s[8], s[9]), fmaxf(s[10], s[11]));
    float t3 = fmaxf(fmaxf(s[12], s[13]), fmaxf(s[14], s[15]));
    float rm = fmaxf(fmaxf(t0, t1), fmaxf(t2, t3));
    rm = fmaxf(rm, __shfl_xor(rm, 32, 64));

    // defer-max (T13): rescale only when max grew by > 8 (log2 domain)
    if (__any(rm > m + 8.0f)) {
      float mn = fmaxf(m, rm);
      float corr = exp2f(m - mn);
      m = mn;
      lsum *= corr;
      cl[w][lq] = corr;          // both halves write identical value
      float cc[16];
#pragma unroll
      for (int r = 0; r < 16; ++r)
        cc[r] = cl[w][(r & 3) + 8 * (r >> 2) + 4 * hi];
#pragma unroll
      for (int db = 0; db < 4; ++db)
#pragma unroll
        for (int r = 0; r < 16; ++r) acc[db][r] *= cc[r];
    }

    // P = exp2(S - m), in-lane partial sum
    float p[16];
    float ps = 0.f;
#pragma unroll
    for (int r = 0; r < 16; ++r) { p[r] = exp2f(s[r] - m); ps += p[r]; }
    lsum += ps + __shfl_xor(ps, 32, 64);

    // T12: pack P into PV A-fragments (cvt_pk + permlane32_swap)
    bf16x8 pa[2];
#pragma unroll
    for (int c = 0; c < 2; ++c) {
      unsigned a0 = cvtpk_bf16(p[8 * c + 0], p[8 * c + 1]);
      unsigned b0 = cvtpk_bf16(p[8 * c + 4], p[8 * c + 5]);
      unsigned a1 = cvtpk_bf16(p[8 * c + 2], p[8 * c + 3]);
      unsigned b1 = cvtpk_bf16(p[8 * c + 6], p[8 * c + 7]);
      asm("v_permlane32_swap_b32 %0, %1" : "+v"(a0), "+v"(b0));
      asm("v_permlane32_swap_b32 %0, %1" : "+v"(a1), "+v"(b1));
      u32x4 w4 = {a0, a1, b0, b1};
      pa[c] = __builtin_bit_cast(bf16x8, w4);
    }

    // PV: acc[db] += P(32q x 32k) * V(32k x 32d)
#pragma unroll
    for (int db = 0; db < 4; ++db) {
      const unsigned short* vr = vbase + (long)(db * 32 + lq) * MROWS + kt;
      bf16x8 v0 = *(const bf16x8*)(vr);
      bf16x8 v1 = *(const bf16x8*)(vr + 16);
      acc[db] = __builtin_amdgcn_mfma_f32_32x32x16_bf16(pa[0], v0, acc[db], 0, 0, 0);
      acc[db] = __builtin_amdgcn_mfma_f32_32x32x16_bf16(pa[1], v1, acc[db], 0, 0, 0);
    }
  }

  // final 1/lsum, transposed to C-domain, then store
  float il = 1.0f / lsum;
  cl[w][lq] = il;
  float ic[16];
#pragma unroll
  for (int r = 0; r < 16; ++r)
    ic[r] = cl[w][(r & 3) + 8 * (r >> 2) + 4 * hi];
#pragma unroll
  for (int db = 0; db < 4; ++db)
#pragma unroll
    for (int r = 0; r < 16; ++r) {
      int row = (r & 3) + 8 * (r >> 2) + 4 * hi;
      O[(long)(b * SEQ + q0 + row) * HID + h * HDIM + db * 32 + lq] =
          f2bf(acc[db][r] * ic[r]);
    }
}

// ------------------------------------------------------------------- launcher
extern "C" void kernel_launch(void* const* d_in, const int* in_sizes, int n_in,
                              void* d_out, int out_size, void* d_ws, size_t ws_size,
                              hipStream_t stream) {
  (void)in_sizes; (void)n_in; (void)out_size; (void)ws_size;
  const int*   positions = (const int*)d_in[0];
  const float* hs = (const float*)d_in[1];
  const float* wq = (const float*)d_in[2];
  const float* wk = (const float*)d_in[3];
  const float* wv = (const float*)d_in[4];
  const float* wo = (const float*)d_in[5];
  const float* qw = (const float*)d_in[6];
  const float* kw = (const float*)d_in[7];

  char* ws = (char*)d_ws;                                   // 160 MB total
  unsigned short* hs_b = (unsigned short*)(ws);              // 32 MB
  unsigned short* wq_b = (unsigned short*)(ws + 33554432);   // 32 MB (reused as attn-out)
  unsigned short* wk_b = (unsigned short*)(ws + 67108864);   //  8 MB
  unsigned short* wv_b = (unsigned short*)(ws + 75497472);   //  8 MB
  unsigned short* wo_b = (unsigned short*)(ws + 83886080);   // 32 MB
  unsigned short* q_b  = (unsigned short*)(ws + 117440512);  // 32 MB
  unsigned short* k_b  = (unsigned short*)(ws + 150994944);  //  8 MB
  unsigned short* vt_b = (unsigned short*)(ws + 159383552);  //  8 MB
  unsigned short* ao_b = wq_b;  // wq dead after Q-proj; alias for attention out

  // f32 -> bf16 conversions
  cvt_kernel<<<dim3((16777216 / 8 + 255) / 256), dim3(256), 0, stream>>>(hs, hs_b, 16777216 / 8);
  cvt_kernel<<<dim3((16777216 / 8 + 255) / 256), dim3(256), 0, stream>>>(wq, wq_b, 16777216 / 8);
  cvt_kernel<<<dim3((4194304 / 8 + 255) / 256), dim3(256), 0, stream>>>(wk, wk_b, 4194304 / 8);
  cvt_kernel<<<dim3((4194304 / 8 + 255) / 256), dim3(256), 0, stream>>>(wv, wv_b, 4194304 / 8);
  cvt_kernel<<<dim3((16777216 / 8 + 255) / 256), dim3(256), 0, stream>>>(wo, wo_b, 16777216 / 8);

  // projections
  gemm_bt<0><<<dim3(32, 32), dim3(256), 0, stream>>>(hs_b, wq_b, q_b, 4096, 4096, 4096, 4096);
  gemm_bt<0><<<dim3(8, 32), dim3(256), 0, stream>>>(hs_b, wk_b, k_b, 4096, 1024, 4096, 1024);
  gemm_bt<2><<<dim3(8, 32), dim3(256), 0, stream>>>(hs_b, wv_b, vt_b, 4096, 1024, 4096, 4096);

  // per-head RMSNorm + RoPE (in place)
  normrope_kernel<<<dim3(32768), dim3(256), 0, stream>>>(q_b, qw, positions, 5, 4096);
  normrope_kernel<<<dim3(8192), dim3(256), 0, stream>>>(k_b, kw, positions, 3, 1024);

  // attention (32x32 swapped structure): 4b x 32h x 8 q-blocks = 1024 blocks
  attn_kernel<<<dim3(1024), dim3(256), 0, stream>>>(q_b, k_b, vt_b, ao_b);

  // output projection -> f32 d_out
  gemm_bt<1><<<dim3(32, 32), dim3(256), 0, stream>>>(ao_b, wo_b, (float*)d_out, 4096, 4096, 4096, 4096);
}

// Round 4
// 709.517 us; speedup vs baseline: 1.4620x; 1.1534x over previous
//
#include <hip/hip_runtime.h>
#include <math.h>

// Problem constants (B=4, S=1024, HIDDEN=4096, H=32, KV=8, D=128)
#define SEQ    1024
#define BATCH  4
#define MROWS  4096          // B*S
#define HID    4096
#define NHEADS 32
#define NKV    8
#define HDIM   128

typedef __bf16 bf16x8 __attribute__((ext_vector_type(8)));
typedef float  f32x4  __attribute__((ext_vector_type(4)));
typedef float  f32x16 __attribute__((ext_vector_type(16)));
typedef unsigned short u16x8 __attribute__((ext_vector_type(8)));
typedef unsigned short u16x4 __attribute__((ext_vector_type(4)));
typedef unsigned int   u32x4 __attribute__((ext_vector_type(4)));

static __device__ __forceinline__ unsigned short f2bf(float f) {
  union { float f; unsigned u; } x; x.f = f;
  unsigned r = x.u + 0x7fffu + ((x.u >> 16) & 1u);   // RNE
  return (unsigned short)(r >> 16);
}
static __device__ __forceinline__ float bf2f(unsigned short h) {
  union { unsigned u; float f; } x; x.u = ((unsigned)h) << 16;
  return x.f;
}
static __device__ __forceinline__ unsigned cvtpk_bf16(float lo, float hi) {
  unsigned r;
  asm("v_cvt_pk_bf16_f32 %0, %1, %2" : "=v"(r) : "v"(lo), "v"(hi));
  return r;
}

// async global->LDS, 16B per lane; LDS dest is wave-uniform base + lane*16
static __device__ __forceinline__ void gload16(const unsigned short* g, unsigned short* l) {
  __builtin_amdgcn_global_load_lds(
      (const __attribute__((address_space(1))) unsigned int*)g,
      (__attribute__((address_space(3))) unsigned int*)l, 16, 0, 0);
}

// ---------------------------------------------------------------- f32 -> bf16
__global__ __launch_bounds__(256) void cvt_kernel(const float* __restrict__ in,
                                                  unsigned short* __restrict__ out,
                                                  int n8) {
  int i = blockIdx.x * 256 + threadIdx.x;
  if (i >= n8) return;
  f32x4 a = ((const f32x4*)in)[2 * i];
  f32x4 b = ((const f32x4*)in)[2 * i + 1];
  u16x8 o;
  o[0] = f2bf(a[0]); o[1] = f2bf(a[1]); o[2] = f2bf(a[2]); o[3] = f2bf(a[3]);
  o[4] = f2bf(b[0]); o[5] = f2bf(b[1]); o[6] = f2bf(b[2]); o[7] = f2bf(b[3]);
  ((u16x8*)out)[i] = o;
}

// ------------------------------------------------------- C = A * B^T (128² tile)
// Kept for the K/V projections (N=1024: 256² tile would under-occupy).
template <int OUTMODE>
__global__ __launch_bounds__(256) void gemm_bt(const unsigned short* __restrict__ A,
                                               const unsigned short* __restrict__ B,
                                               void* __restrict__ Cp,
                                               int M, int N, int K, int ldc) {
  __shared__ unsigned short As[4096];   // [128][32]
  __shared__ unsigned short Bs[4096];
  const int t  = threadIdx.x;
  const int l  = t & 63, w = t >> 6;
  const int wr = w >> 1, wc = w & 1;
  const int lr = l & 15, lg = l >> 4;
  const int m0 = blockIdx.y * 128, n0 = blockIdx.x * 128;

  const int srow = t >> 2;
  const int skg  = (t & 3) ^ (srow & 3);
  const unsigned short* ga0 = A + (long)(m0 + srow) * K + skg * 8;
  const unsigned short* ga1 = ga0 + 64L * K;
  const unsigned short* gb0 = B + (long)(n0 + srow) * K + skg * 8;
  const unsigned short* gb1 = gb0 + 64L * K;

  int aro[4], bro[4];
#pragma unroll
  for (int i = 0; i < 4; ++i) {
    aro[i] = (wr * 64 + i * 16 + lr) * 32 + ((lg ^ (lr & 3)) * 8);
    bro[i] = (wc * 64 + i * 16 + lr) * 32 + ((lg ^ (lr & 3)) * 8);
  }

  f32x4 acc[4][4] = {};
  for (int k0 = 0; k0 < K; k0 += 32) {
    if (k0) __syncthreads();
    gload16(ga0 + k0, As + (w << 9));
    gload16(ga1 + k0, As + 2048 + (w << 9));
    gload16(gb0 + k0, Bs + (w << 9));
    gload16(gb1 + k0, Bs + 2048 + (w << 9));
    __syncthreads();
    bf16x8 af[4], bfv[4];
#pragma unroll
    for (int i = 0; i < 4; ++i) af[i]  = *(const bf16x8*)(As + aro[i]);
#pragma unroll
    for (int i = 0; i < 4; ++i) bfv[i] = *(const bf16x8*)(Bs + bro[i]);
#pragma unroll
    for (int mi = 0; mi < 4; ++mi)
#pragma unroll
      for (int ni = 0; ni < 4; ++ni)
        acc[mi][ni] = __builtin_amdgcn_mfma_f32_16x16x32_bf16(af[mi], bfv[ni],
                                                              acc[mi][ni], 0, 0, 0);
  }

  const int r0 = m0 + wr * 64 + lg * 4;
  const int c0 = n0 + wc * 64 + lr;
  if (OUTMODE == 0) {
    unsigned short* C = (unsigned short*)Cp;
#pragma unroll
    for (int mi = 0; mi < 4; ++mi)
#pragma unroll
      for (int ni = 0; ni < 4; ++ni)
#pragma unroll
        for (int j = 0; j < 4; ++j)
          C[(long)(r0 + mi * 16 + j) * ldc + (c0 + ni * 16)] = f2bf(acc[mi][ni][j]);
  } else if (OUTMODE == 1) {
    float* C = (float*)Cp;
#pragma unroll
    for (int mi = 0; mi < 4; ++mi)
#pragma unroll
      for (int ni = 0; ni < 4; ++ni)
#pragma unroll
        for (int j = 0; j < 4; ++j)
          C[(long)(r0 + mi * 16 + j) * ldc + (c0 + ni * 16)] = acc[mi][ni][j];
  } else {
    unsigned short* C = (unsigned short*)Cp;   // C^T[N][M], ldc = M
#pragma unroll
    for (int mi = 0; mi < 4; ++mi)
#pragma unroll
      for (int ni = 0; ni < 4; ++ni) {
        u16x4 v;
#pragma unroll
        for (int j = 0; j < 4; ++j) v[j] = f2bf(acc[mi][ni][j]);
        *(u16x4*)(C + (long)(c0 + ni * 16) * ldc + (r0 + mi * 16)) = v;
      }
  }
}

// ---------------------------------------------- 256² 8-phase GEMM (T2+T3+T4+T5)
// C = A * B^T, M=N=K=4096 fixed. 8 waves (2M x 4N), BK=64, 128 KiB LDS:
// 2 dbuf x {A,B} x 2 halves(128 rows x 64 k). Quadrant phases per tile:
// (0,0),(0,1),(1,1),(1,0) with B0 regs held p1->p4, so half-tiles free at
// phases 1/2/3; stage exactly the freed half: p1:t1.A1 p2:t2.A0 p3:t2.B0
// p4:t2.B1 p5:t2.A1 p6:t3.A0 p7:t3.B0 p8:t3.B1; vmcnt(6) at p4/p8 forces
// next tile landed (3 youngest half-tiles stay in flight). Swizzle
// byte^=((row&7)<<4): linear gload_lds dest + inverse-swizzled global src
// + swizzled ds_read (rule #21).
#define BAR8 __builtin_amdgcn_s_barrier()
#define WL0  do { asm volatile("s_waitcnt lgkmcnt(0)" ::: "memory"); \
                  __builtin_amdgcn_sched_barrier(0); } while (0)
#define WV6  asm volatile("s_waitcnt vmcnt(6)" ::: "memory")

template <int OUTMODE>
__global__ __launch_bounds__(512, 2) void gemm8_bt(const unsigned short* __restrict__ A,
                                                   const unsigned short* __restrict__ B,
                                                   void* __restrict__ Cp) {
  __shared__ unsigned short lds[65536];        // 128 KiB
  const int t = threadIdx.x, l = t & 63, w = t >> 6;
  const int wr = w >> 2, wc = w & 3;
  const int lr = l & 15, lg = l >> 4;
  const int bid = blockIdx.x;
  const int swz = (bid & 7) * 32 + (bid >> 3);  // XCD swizzle (256 % 8 == 0)
  const int m0 = (swz >> 4) << 8, n0 = (swz & 15) << 8;
  const long K = 4096;

  // staging per-lane statics: lane covers LDS bytes chunk*1024 + l*16;
  // row-in-chunk = l>>3; swizzled source col = ((l&7)^(l>>3))*8 elements
  const int rc = l >> 3;
  const int ce = ((l & 7) ^ rc) << 3;

#define STGA(d, h, tt) do { \
    const unsigned short* _s = A + (long)(m0 + (h)*128 + w*8 + rc) * K + (long)(tt)*64 + ce; \
    gload16(_s,            lds + ((d)*2+(h))*8192 + w*512); \
    gload16(_s + 64L * K,  lds + ((d)*2+(h))*8192 + (8 + w)*512); \
  } while (0)
#define STGB(d, h, tt) do { \
    const unsigned short* _s = B + (long)(n0 + (h)*128 + w*8 + rc) * K + (long)(tt)*64 + ce; \
    gload16(_s,            lds + 32768 + ((d)*2+(h))*8192 + w*512); \
    gload16(_s + 64L * K,  lds + 32768 + ((d)*2+(h))*8192 + (8 + w)*512); \
  } while (0)
#define LDA8(d, rh) do { \
    _Pragma("unroll") for (int ri = 0; ri < 4; ++ri) \
    _Pragma("unroll") for (int kk = 0; kk < 2; ++kk) { \
      int r  = wr*64 + ri*16 + lr; \
      int cb = (kk*64 + lg*16) ^ ((l & 7) << 4); \
      a[ri][kk] = *(const bf16x8*)(lds + ((d)*2+(rh))*8192 + r*64 + (cb >> 1)); \
    } } while (0)
#define LDB8(d, ch, barr) do { \
    _Pragma("unroll") for (int ci = 0; ci < 2; ++ci) \
    _Pragma("unroll") for (int kk = 0; kk < 2; ++kk) { \
      int r  = wc*32 + ci*16 + lr; \
      int cb = (kk*64 + lg*16) ^ ((l & 7) << 4); \
      barr[ci][kk] = *(const bf16x8*)(lds + 32768 + ((d)*2+(ch))*8192 + r*64 + (cb >> 1)); \
    } } while (0)
#define MM8(rh, ch, barr) do { \
    __builtin_amdgcn_s_setprio(1); \
    _Pragma("unroll") for (int kk = 0; kk < 2; ++kk) \
    _Pragma("unroll") for (int ri = 0; ri < 4; ++ri) \
    _Pragma("unroll") for (int ci = 0; ci < 2; ++ci) \
      acc[rh][ch][ri][ci] = __builtin_amdgcn_mfma_f32_16x16x32_bf16( \
          a[ri][kk], barr[ci][kk], acc[rh][ch][ri][ci], 0, 0, 0); \
    __builtin_amdgcn_s_setprio(0); \
  } while (0)

  f32x4 acc[2][2][4][2] = {};
  bf16x8 a[4][2], b0[2][2], b1[2][2];

  // prologue: t0 all 4 halves + t1 {A0,B0,B1}; leave t1's 3 in flight
  STGA(0, 0, 0); STGB(0, 0, 0); STGB(0, 1, 0); STGA(0, 1, 0);
  STGA(1, 0, 1); STGB(1, 0, 1); STGB(1, 1, 1);
  WV6;
  BAR8;

  for (int i = 0; i < 32; ++i) {
    const int t1 = 2 * i + 1, t2 = (2 * i + 2) & 63, t3 = (2 * i + 3) & 63;
    // p1: quadrant (0,0) of tile 2i (dbuf0)
    LDA8(0, 0); LDB8(0, 0, b0);
    STGA(1, 1, t1);
    BAR8; WL0; MM8(0, 0, b0); BAR8;
    // p2: (0,1) — reuse a
    LDB8(0, 1, b1);
    STGA(0, 0, t2);
    BAR8; WL0; MM8(0, 1, b1); BAR8;
    // p3: (1,1) — reuse b1
    LDA8(0, 1);
    STGB(0, 0, t2);
    BAR8; WL0; MM8(1, 1, b1); BAR8;
    // p4: (1,0) — reuse a, b0
    STGB(0, 1, t2);
    WV6;
    BAR8; WL0; MM8(1, 0, b0); BAR8;
    // p5: quadrant (0,0) of tile 2i+1 (dbuf1)
    LDA8(1, 0); LDB8(1, 0, b0);
    STGA(0, 1, t2);
    BAR8; WL0; MM8(0, 0, b0); BAR8;
    // p6
    LDB8(1, 1, b1);
    STGA(1, 0, t3);
    BAR8; WL0; MM8(0, 1, b1); BAR8;
    // p7
    LDA8(1, 1);
    STGB(1, 0, t3);
    BAR8; WL0; MM8(1, 1, b1); BAR8;
    // p8
    STGB(1, 1, t3);
    WV6;
    BAR8; WL0; MM8(1, 0, b0); BAR8;
  }

  // epilogue: C-write (C/D layout: col = lane&15, row = (lane>>4)*4 + j)
#pragma unroll
  for (int rh = 0; rh < 2; ++rh)
#pragma unroll
    for (int ch = 0; ch < 2; ++ch)
#pragma unroll
      for (int ri = 0; ri < 4; ++ri)
#pragma unroll
        for (int ci = 0; ci < 2; ++ci)
#pragma unroll
          for (int j = 0; j < 4; ++j) {
            const int row = m0 + rh * 128 + wr * 64 + ri * 16 + lg * 4 + j;
            const int col = n0 + ch * 128 + wc * 32 + ci * 16 + lr;
            if (OUTMODE == 0)
              ((unsigned short*)Cp)[(long)row * 4096 + col] = f2bf(acc[rh][ch][ri][ci][j]);
            else
              ((float*)Cp)[(long)row * 4096 + col] = acc[rh][ch][ri][ci][j];
          }
#undef STGA
#undef STGB
#undef LDA8
#undef LDB8
#undef MM8
}

// --------------------------------------------- fused per-head RMSNorm + RoPE
__global__ __launch_bounds__(256) void normrope_kernel(unsigned short* __restrict__ X,
                                                       const float* __restrict__ wnorm,
                                                       const int* __restrict__ positions,
                                                       int hshift, int stride) {
  const int t = threadIdx.x, l = t & 63, wv = t >> 6;
  const int slice = blockIdx.x * 4 + wv;
  const int head  = slice & ((1 << hshift) - 1);
  const int row   = slice >> hshift;
  const int s     = row & (SEQ - 1);
  unsigned short* p = X + (long)row * stride + (head << 7);

  float x1 = bf2f(p[l]), x2 = bf2f(p[l + 64]);
  float ss = x1 * x1 + x2 * x2;
#pragma unroll
  for (int m = 1; m < 64; m <<= 1) ss += __shfl_xor(ss, m, 64);
  float inv = rsqrtf(ss * (1.0f / 128.0f) + 1e-6f);
  x1 *= inv * wnorm[l];
  x2 *= inv * wnorm[l + 64];

  float invf = exp2f((float)l * -0.31143075889569023f);
  float ang  = (float)positions[s] * invf;
  float sn, cs;
  sincosf(ang, &sn, &cs);
  p[l]      = f2bf(x1 * cs - x2 * sn);
  p[l + 64] = f2bf(x2 * cs + x1 * sn);
}

// ------------------------------------------------------------ flash attention
// 32x32 swapped-QK^T structure (guide §B / m214) — unchanged from R3 (passed).
__global__ __launch_bounds__(256) void attn_kernel(const unsigned short* __restrict__ Q,
                                                   const unsigned short* __restrict__ K,
                                                   const unsigned short* __restrict__ Vt,
                                                   unsigned short* __restrict__ O) {
  __shared__ float cl[4][32];   // per-wave corr/invl transpose (P-domain -> C-domain)
  const int t = threadIdx.x, l = t & 63, w = t >> 6;
  const int lq = l & 31, hi = l >> 5;
  const int blk = blockIdx.x;
  const int qb = blk & 7, h = (blk >> 3) & 31, b = blk >> 8;
  const int kv = h >> 2;                     // GQA: 4 q-heads per kv-head
  const int q0 = qb * 128 + w * 32;

  const float qsc = 0.12751791438584222f;    // (1/sqrt(128)) * log2(e)
  bf16x8 qf[8];
  const unsigned short* qrow = Q + (long)(b * SEQ + q0 + lq) * HID + h * HDIM + 8 * hi;
#pragma unroll
  for (int ks = 0; ks < 8; ++ks) {
    u16x8 raw = *(const u16x8*)(qrow + ks * 16);
    bf16x8 qv;
#pragma unroll
    for (int j = 0; j < 8; ++j) qv[j] = (__bf16)(bf2f(raw[j]) * qsc);
    qf[ks] = qv;
  }

  f32x16 acc[4] = {};
  float m = -3.0e38f, lsum = 0.f;

  const unsigned short* kbase = K + (long)(b * SEQ) * (NKV * HDIM) + kv * HDIM + 8 * hi;
  const unsigned short* vbase = Vt + (long)(kv * HDIM) * MROWS + (long)b * SEQ + 8 * hi;

  for (int kt = 0; kt < SEQ; kt += 32) {
    f32x16 s = {};
    const unsigned short* kr = kbase + (long)(kt + lq) * (NKV * HDIM);
#pragma unroll
    for (int ks = 0; ks < 8; ++ks) {
      bf16x8 kf = *(const bf16x8*)(kr + ks * 16);
      s = __builtin_amdgcn_mfma_f32_32x32x16_bf16(kf, qf[ks], s, 0, 0, 0);
    }

    float t0 = fmaxf(fmaxf(s[0], s[1]), fmaxf(s[2], s[3]));
    float t1 = fmaxf(fmaxf(s[4], s[5]), fmaxf(s[6], s[7]));
    float t2 = fmaxf(fmaxf(s[8], s[9]), fmaxf(s[10], s[11]));
    float t3 = fmaxf(fmaxf(s[12], s[13]), fmaxf(s[14], s[15]));
    float rm = fmaxf(fmaxf(t0, t1), fmaxf(t2, t3));
    rm = fmaxf(rm, __shfl_xor(rm, 32, 64));

    if (__any(rm > m + 8.0f)) {
      float mn = fmaxf(m, rm);
      float corr = exp2f(m - mn);
      m = mn;
      lsum *= corr;
      cl[w][lq] = corr;
      float cc[16];
#pragma unroll
      for (int r = 0; r < 16; ++r)
        cc[r] = cl[w][(r & 3) + 8 * (r >> 2) + 4 * hi];
#pragma unroll
      for (int db = 0; db < 4; ++db)
#pragma unroll
        for (int r = 0; r < 16; ++r) acc[db][r] *= cc[r];
    }

    float p[16];
    float ps = 0.f;
#pragma unroll
    for (int r = 0; r < 16; ++r) { p[r] = exp2f(s[r] - m); ps += p[r]; }
    lsum += ps + __shfl_xor(ps, 32, 64);

    bf16x8 pa[2];
#pragma unroll
    for (int c = 0; c < 2; ++c) {
      unsigned a0 = cvtpk_bf16(p[8 * c + 0], p[8 * c + 1]);
      unsigned b0 = cvtpk_bf16(p[8 * c + 4], p[8 * c + 5]);
      unsigned a1 = cvtpk_bf16(p[8 * c + 2], p[8 * c + 3]);
      unsigned b1 = cvtpk_bf16(p[8 * c + 6], p[8 * c + 7]);
      asm("v_permlane32_swap_b32 %0, %1" : "+v"(a0), "+v"(b0));
      asm("v_permlane32_swap_b32 %0, %1" : "+v"(a1), "+v"(b1));
      u32x4 w4 = {a0, a1, b0, b1};
      pa[c] = __builtin_bit_cast(bf16x8, w4);
    }

#pragma unroll
    for (int db = 0; db < 4; ++db) {
      const unsigned short* vr = vbase + (long)(db * 32 + lq) * MROWS + kt;
      bf16x8 v0 = *(const bf16x8*)(vr);
      bf16x8 v1 = *(const bf16x8*)(vr + 16);
      acc[db] = __builtin_amdgcn_mfma_f32_32x32x16_bf16(pa[0], v0, acc[db], 0, 0, 0);
      acc[db] = __builtin_amdgcn_mfma_f32_32x32x16_bf16(pa[1], v1, acc[db], 0, 0, 0);
    }
  }

  float il = 1.0f / lsum;
  cl[w][lq] = il;
  float ic[16];
#pragma unroll
  for (int r = 0; r < 16; ++r)
    ic[r] = cl[w][(r & 3) + 8 * (r >> 2) + 4 * hi];
#pragma unroll
  for (int db = 0; db < 4; ++db)
#pragma unroll
    for (int r = 0; r < 16; ++r) {
      int row = (r & 3) + 8 * (r >> 2) + 4 * hi;
      O[(long)(b * SEQ + q0 + row) * HID + h * HDIM + db * 32 + lq] =
          f2bf(acc[db][r] * ic[r]);
    }
}

// ------------------------------------------------------------------- launcher
extern "C" void kernel_launch(void* const* d_in, const int* in_sizes, int n_in,
                              void* d_out, int out_size, void* d_ws, size_t ws_size,
                              hipStream_t stream) {
  (void)in_sizes; (void)n_in; (void)out_size; (void)ws_size;
  const int*   positions = (const int*)d_in[0];
  const float* hs = (const float*)d_in[1];
  const float* wq = (const float*)d_in[2];
  const float* wk = (const float*)d_in[3];
  const float* wv = (const float*)d_in[4];
  const float* wo = (const float*)d_in[5];
  const float* qw = (const float*)d_in[6];
  const float* kw = (const float*)d_in[7];

  char* ws = (char*)d_ws;                                   // 160 MB total
  unsigned short* hs_b = (unsigned short*)(ws);              // 32 MB
  unsigned short* wq_b = (unsigned short*)(ws + 33554432);   // 32 MB (reused as attn-out)
  unsigned short* wk_b = (unsigned short*)(ws + 67108864);   //  8 MB
  unsigned short* wv_b = (unsigned short*)(ws + 75497472);   //  8 MB
  unsigned short* wo_b = (unsigned short*)(ws + 83886080);   // 32 MB
  unsigned short* q_b  = (unsigned short*)(ws + 117440512);  // 32 MB
  unsigned short* k_b  = (unsigned short*)(ws + 150994944);  //  8 MB
  unsigned short* vt_b = (unsigned short*)(ws + 159383552);  //  8 MB
  unsigned short* ao_b = wq_b;  // wq dead after Q-proj; alias for attention out

  // f32 -> bf16 conversions
  cvt_kernel<<<dim3((16777216 / 8 + 255) / 256), dim3(256), 0, stream>>>(hs, hs_b, 16777216 / 8);
  cvt_kernel<<<dim3((16777216 / 8 + 255) / 256), dim3(256), 0, stream>>>(wq, wq_b, 16777216 / 8);
  cvt_kernel<<<dim3((4194304 / 8 + 255) / 256), dim3(256), 0, stream>>>(wk, wk_b, 4194304 / 8);
  cvt_kernel<<<dim3((4194304 / 8 + 255) / 256), dim3(256), 0, stream>>>(wv, wv_b, 4194304 / 8);
  cvt_kernel<<<dim3((16777216 / 8 + 255) / 256), dim3(256), 0, stream>>>(wo, wo_b, 16777216 / 8);

  // projections: Q via 8-phase 256² template; K/V via 128² template
  gemm8_bt<0><<<dim3(256), dim3(512), 0, stream>>>(hs_b, wq_b, q_b);
  gemm_bt<0><<<dim3(8, 32), dim3(256), 0, stream>>>(hs_b, wk_b, k_b, 4096, 1024, 4096, 1024);
  gemm_bt<2><<<dim3(8, 32), dim3(256), 0, stream>>>(hs_b, wv_b, vt_b, 4096, 1024, 4096, 4096);

  // per-head RMSNorm + RoPE (in place)
  normrope_kernel<<<dim3(32768), dim3(256), 0, stream>>>(q_b, qw, positions, 5, 4096);
  normrope_kernel<<<dim3(8192), dim3(256), 0, stream>>>(k_b, kw, positions, 3, 1024);

  // attention (32x32 swapped structure): 4b x 32h x 8 q-blocks = 1024 blocks
  attn_kernel<<<dim3(1024), dim3(256), 0, stream>>>(q_b, k_b, vt_b, ao_b);

  // output projection -> f32 d_out (8-phase 256² template)
  gemm8_bt<1><<<dim3(256), dim3(512), 0, stream>>>(ao_b, wo_b, (float*)d_out);
}

// Round 5
// 705.835 us; speedup vs baseline: 1.4696x; 1.0052x over previous
//
#include <hip/hip_runtime.h>
#include <math.h>

// Problem constants (B=4, S=1024, HIDDEN=4096, H=32, KV=8, D=128)
#define SEQ    1024
#define BATCH  4
#define MROWS  4096          // B*S
#define HID    4096
#define NHEADS 32
#define NKV    8
#define HDIM   128

typedef __bf16 bf16x8 __attribute__((ext_vector_type(8)));
typedef float  f32x4  __attribute__((ext_vector_type(4)));
typedef float  f32x16 __attribute__((ext_vector_type(16)));
typedef unsigned short u16x8 __attribute__((ext_vector_type(8)));
typedef unsigned short u16x4 __attribute__((ext_vector_type(4)));
typedef unsigned int   u32x4 __attribute__((ext_vector_type(4)));

static __device__ __forceinline__ unsigned short f2bf(float f) {
  union { float f; unsigned u; } x; x.f = f;
  unsigned r = x.u + 0x7fffu + ((x.u >> 16) & 1u);   // RNE
  return (unsigned short)(r >> 16);
}
static __device__ __forceinline__ float bf2f(unsigned short h) {
  union { unsigned u; float f; } x; x.u = ((unsigned)h) << 16;
  return x.f;
}
static __device__ __forceinline__ unsigned cvtpk_bf16(float lo, float hi) {
  unsigned r;
  asm("v_cvt_pk_bf16_f32 %0, %1, %2" : "=v"(r) : "v"(lo), "v"(hi));
  return r;
}

// async global->LDS, 16B per lane; LDS dest is wave-uniform base + lane*16
static __device__ __forceinline__ void gload16(const unsigned short* g, unsigned short* l) {
  __builtin_amdgcn_global_load_lds(
      (const __attribute__((address_space(1))) unsigned int*)g,
      (__attribute__((address_space(3))) unsigned int*)l, 16, 0, 0);
}

// ---------------------------------------------------------------- f32 -> bf16
__global__ __launch_bounds__(256) void cvt_kernel(const float* __restrict__ in,
                                                  unsigned short* __restrict__ out,
                                                  int n8) {
  int i = blockIdx.x * 256 + threadIdx.x;
  if (i >= n8) return;
  f32x4 a = ((const f32x4*)in)[2 * i];
  f32x4 b = ((const f32x4*)in)[2 * i + 1];
  u16x8 o;
  o[0] = f2bf(a[0]); o[1] = f2bf(a[1]); o[2] = f2bf(a[2]); o[3] = f2bf(a[3]);
  o[4] = f2bf(b[0]); o[5] = f2bf(b[1]); o[6] = f2bf(b[2]); o[7] = f2bf(b[3]);
  ((u16x8*)out)[i] = o;
}

// ------------------------------------------------------- C = A * B^T (128² tile)
// Kept for the K/V projections (N=1024: 256² tile would under-occupy).
template <int OUTMODE>
__global__ __launch_bounds__(256) void gemm_bt(const unsigned short* __restrict__ A,
                                               const unsigned short* __restrict__ B,
                                               void* __restrict__ Cp,
                                               int M, int N, int K, int ldc) {
  __shared__ unsigned short As[4096];   // [128][32]
  __shared__ unsigned short Bs[4096];
  const int t  = threadIdx.x;
  const int l  = t & 63, w = t >> 6;
  const int wr = w >> 1, wc = w & 1;
  const int lr = l & 15, lg = l >> 4;
  const int m0 = blockIdx.y * 128, n0 = blockIdx.x * 128;

  const int srow = t >> 2;
  const int skg  = (t & 3) ^ (srow & 3);
  const unsigned short* ga0 = A + (long)(m0 + srow) * K + skg * 8;
  const unsigned short* ga1 = ga0 + 64L * K;
  const unsigned short* gb0 = B + (long)(n0 + srow) * K + skg * 8;
  const unsigned short* gb1 = gb0 + 64L * K;

  int aro[4], bro[4];
#pragma unroll
  for (int i = 0; i < 4; ++i) {
    aro[i] = (wr * 64 + i * 16 + lr) * 32 + ((lg ^ (lr & 3)) * 8);
    bro[i] = (wc * 64 + i * 16 + lr) * 32 + ((lg ^ (lr & 3)) * 8);
  }

  f32x4 acc[4][4] = {};
  for (int k0 = 0; k0 < K; k0 += 32) {
    if (k0) __syncthreads();
    gload16(ga0 + k0, As + (w << 9));
    gload16(ga1 + k0, As + 2048 + (w << 9));
    gload16(gb0 + k0, Bs + (w << 9));
    gload16(gb1 + k0, Bs + 2048 + (w << 9));
    __syncthreads();
    bf16x8 af[4], bfv[4];
#pragma unroll
    for (int i = 0; i < 4; ++i) af[i]  = *(const bf16x8*)(As + aro[i]);
#pragma unroll
    for (int i = 0; i < 4; ++i) bfv[i] = *(const bf16x8*)(Bs + bro[i]);
#pragma unroll
    for (int mi = 0; mi < 4; ++mi)
#pragma unroll
      for (int ni = 0; ni < 4; ++ni)
        acc[mi][ni] = __builtin_amdgcn_mfma_f32_16x16x32_bf16(af[mi], bfv[ni],
                                                              acc[mi][ni], 0, 0, 0);
  }

  const int r0 = m0 + wr * 64 + lg * 4;
  const int c0 = n0 + wc * 64 + lr;
  if (OUTMODE == 0) {
    unsigned short* C = (unsigned short*)Cp;
#pragma unroll
    for (int mi = 0; mi < 4; ++mi)
#pragma unroll
      for (int ni = 0; ni < 4; ++ni)
#pragma unroll
        for (int j = 0; j < 4; ++j)
          C[(long)(r0 + mi * 16 + j) * ldc + (c0 + ni * 16)] = f2bf(acc[mi][ni][j]);
  } else if (OUTMODE == 1) {
    float* C = (float*)Cp;
#pragma unroll
    for (int mi = 0; mi < 4; ++mi)
#pragma unroll
      for (int ni = 0; ni < 4; ++ni)
#pragma unroll
        for (int j = 0; j < 4; ++j)
          C[(long)(r0 + mi * 16 + j) * ldc + (c0 + ni * 16)] = acc[mi][ni][j];
  } else {
    unsigned short* C = (unsigned short*)Cp;   // C^T[N][M], ldc = M
#pragma unroll
    for (int mi = 0; mi < 4; ++mi)
#pragma unroll
      for (int ni = 0; ni < 4; ++ni) {
        u16x4 v;
#pragma unroll
        for (int j = 0; j < 4; ++j) v[j] = f2bf(acc[mi][ni][j]);
        *(u16x4*)(C + (long)(c0 + ni * 16) * ldc + (r0 + mi * 16)) = v;
      }
  }
}

// ---------------------------------------------- 256² 8-phase GEMM (T2+T3+T4+T5)
// (unchanged from R4 — verified: ~95 µs per 4096³, MfmaUtil high, pass)
#define BAR8 __builtin_amdgcn_s_barrier()
#define WL0  do { asm volatile("s_waitcnt lgkmcnt(0)" ::: "memory"); \
                  __builtin_amdgcn_sched_barrier(0); } while (0)
#define WV6  asm volatile("s_waitcnt vmcnt(6)" ::: "memory")

template <int OUTMODE>
__global__ __launch_bounds__(512, 2) void gemm8_bt(const unsigned short* __restrict__ A,
                                                   const unsigned short* __restrict__ B,
                                                   void* __restrict__ Cp) {
  __shared__ unsigned short lds[65536];        // 128 KiB
  const int t = threadIdx.x, l = t & 63, w = t >> 6;
  const int wr = w >> 2, wc = w & 3;
  const int lr = l & 15, lg = l >> 4;
  const int bid = blockIdx.x;
  const int swz = (bid & 7) * 32 + (bid >> 3);  // XCD swizzle (256 % 8 == 0)
  const int m0 = (swz >> 4) << 8, n0 = (swz & 15) << 8;
  const long K = 4096;

  const int rc = l >> 3;
  const int ce = ((l & 7) ^ rc) << 3;

#define STGA(d, h, tt) do { \
    const unsigned short* _s = A + (long)(m0 + (h)*128 + w*8 + rc) * K + (long)(tt)*64 + ce; \
    gload16(_s,            lds + ((d)*2+(h))*8192 + w*512); \
    gload16(_s + 64L * K,  lds + ((d)*2+(h))*8192 + (8 + w)*512); \
  } while (0)
#define STGB(d, h, tt) do { \
    const unsigned short* _s = B + (long)(n0 + (h)*128 + w*8 + rc) * K + (long)(tt)*64 + ce; \
    gload16(_s,            lds + 32768 + ((d)*2+(h))*8192 + w*512); \
    gload16(_s + 64L * K,  lds + 32768 + ((d)*2+(h))*8192 + (8 + w)*512); \
  } while (0)
#define LDA8(d, rh) do { \
    _Pragma("unroll") for (int ri = 0; ri < 4; ++ri) \
    _Pragma("unroll") for (int kk = 0; kk < 2; ++kk) { \
      int r  = wr*64 + ri*16 + lr; \
      int cb = (kk*64 + lg*16) ^ ((l & 7) << 4); \
      a[ri][kk] = *(const bf16x8*)(lds + ((d)*2+(rh))*8192 + r*64 + (cb >> 1)); \
    } } while (0)
#define LDB8(d, ch, barr) do { \
    _Pragma("unroll") for (int ci = 0; ci < 2; ++ci) \
    _Pragma("unroll") for (int kk = 0; kk < 2; ++kk) { \
      int r  = wc*32 + ci*16 + lr; \
      int cb = (kk*64 + lg*16) ^ ((l & 7) << 4); \
      barr[ci][kk] = *(const bf16x8*)(lds + 32768 + ((d)*2+(ch))*8192 + r*64 + (cb >> 1)); \
    } } while (0)
#define MM8(rh, ch, barr) do { \
    __builtin_amdgcn_s_setprio(1); \
    _Pragma("unroll") for (int kk = 0; kk < 2; ++kk) \
    _Pragma("unroll") for (int ri = 0; ri < 4; ++ri) \
    _Pragma("unroll") for (int ci = 0; ci < 2; ++ci) \
      acc[rh][ch][ri][ci] = __builtin_amdgcn_mfma_f32_16x16x32_bf16( \
          a[ri][kk], barr[ci][kk], acc[rh][ch][ri][ci], 0, 0, 0); \
    __builtin_amdgcn_s_setprio(0); \
  } while (0)

  f32x4 acc[2][2][4][2] = {};
  bf16x8 a[4][2], b0[2][2], b1[2][2];

  STGA(0, 0, 0); STGB(0, 0, 0); STGB(0, 1, 0); STGA(0, 1, 0);
  STGA(1, 0, 1); STGB(1, 0, 1); STGB(1, 1, 1);
  WV6;
  BAR8;

  for (int i = 0; i < 32; ++i) {
    const int t1 = 2 * i + 1, t2 = (2 * i + 2) & 63, t3 = (2 * i + 3) & 63;
    LDA8(0, 0); LDB8(0, 0, b0);
    STGA(1, 1, t1);
    BAR8; WL0; MM8(0, 0, b0); BAR8;
    LDB8(0, 1, b1);
    STGA(0, 0, t2);
    BAR8; WL0; MM8(0, 1, b1); BAR8;
    LDA8(0, 1);
    STGB(0, 0, t2);
    BAR8; WL0; MM8(1, 1, b1); BAR8;
    STGB(0, 1, t2);
    WV6;
    BAR8; WL0; MM8(1, 0, b0); BAR8;
    LDA8(1, 0); LDB8(1, 0, b0);
    STGA(0, 1, t2);
    BAR8; WL0; MM8(0, 0, b0); BAR8;
    LDB8(1, 1, b1);
    STGA(1, 0, t3);
    BAR8; WL0; MM8(0, 1, b1); BAR8;
    LDA8(1, 1);
    STGB(1, 0, t3);
    BAR8; WL0; MM8(1, 1, b1); BAR8;
    STGB(1, 1, t3);
    WV6;
    BAR8; WL0; MM8(1, 0, b0); BAR8;
  }

#pragma unroll
  for (int rh = 0; rh < 2; ++rh)
#pragma unroll
    for (int ch = 0; ch < 2; ++ch)
#pragma unroll
      for (int ri = 0; ri < 4; ++ri)
#pragma unroll
        for (int ci = 0; ci < 2; ++ci)
#pragma unroll
          for (int j = 0; j < 4; ++j) {
            const int row = m0 + rh * 128 + wr * 64 + ri * 16 + lg * 4 + j;
            const int col = n0 + ch * 128 + wc * 32 + ci * 16 + lr;
            if (OUTMODE == 0)
              ((unsigned short*)Cp)[(long)row * 4096 + col] = f2bf(acc[rh][ch][ri][ci][j]);
            else
              ((float*)Cp)[(long)row * 4096 + col] = acc[rh][ch][ri][ci][j];
          }
#undef STGA
#undef STGB
#undef LDA8
#undef LDB8
#undef MM8
}

// --------------------------------------------- fused per-head RMSNorm + RoPE
__global__ __launch_bounds__(256) void normrope_kernel(unsigned short* __restrict__ X,
                                                       const float* __restrict__ wnorm,
                                                       const int* __restrict__ positions,
                                                       int hshift, int stride) {
  const int t = threadIdx.x, l = t & 63, wv = t >> 6;
  const int slice = blockIdx.x * 4 + wv;
  const int head  = slice & ((1 << hshift) - 1);
  const int row   = slice >> hshift;
  const int s     = row & (SEQ - 1);
  unsigned short* p = X + (long)row * stride + (head << 7);

  float x1 = bf2f(p[l]), x2 = bf2f(p[l + 64]);
  float ss = x1 * x1 + x2 * x2;
#pragma unroll
  for (int m = 1; m < 64; m <<= 1) ss += __shfl_xor(ss, m, 64);
  float inv = rsqrtf(ss * (1.0f / 128.0f) + 1e-6f);
  x1 *= inv * wnorm[l];
  x2 *= inv * wnorm[l + 64];

  float invf = exp2f((float)l * -0.31143075889569023f);
  float ang  = (float)positions[s] * invf;
  float sn, cs;
  sincosf(ang, &sn, &cs);
  p[l]      = f2bf(x1 * cs - x2 * sn);
  p[l + 64] = f2bf(x2 * cs + x1 * sn);
}

// ------------------------------------------------------------ flash attention
// 32x32 swapped-QK^T + T14-style register pipeline:
//   V-loads issued at loop top (hide under QK^T+softmax),
//   next-tile K prefetch issued after QK^T (hide under softmax+PV),
//   unroll-2 so kf/kn double-buffer is register rotation.
__global__ __launch_bounds__(256) void attn_kernel(const unsigned short* __restrict__ Q,
                                                   const unsigned short* __restrict__ K,
                                                   const unsigned short* __restrict__ Vt,
                                                   unsigned short* __restrict__ O) {
  __shared__ float cl[4][32];   // per-wave corr/invl transpose (P-domain -> C-domain)
  const int t = threadIdx.x, l = t & 63, w = t >> 6;
  const int lq = l & 31, hi = l >> 5;
  const int blk = blockIdx.x;
  const int qb = blk & 7, h = (blk >> 3) & 31, b = blk >> 8;
  const int kv = h >> 2;                     // GQA: 4 q-heads per kv-head
  const int q0 = qb * 128 + w * 32;
  const int NKVD = NKV * HDIM;               // 1024

  const float qsc = 0.12751791438584222f;    // (1/sqrt(128)) * log2(e)
  bf16x8 qf[8];
  const unsigned short* qrow = Q + (long)(b * SEQ + q0 + lq) * HID + h * HDIM + 8 * hi;
#pragma unroll
  for (int ks = 0; ks < 8; ++ks) {
    u16x8 raw = *(const u16x8*)(qrow + ks * 16);
    bf16x8 qv;
#pragma unroll
    for (int j = 0; j < 8; ++j) qv[j] = (__bf16)(bf2f(raw[j]) * qsc);
    qf[ks] = qv;
  }

  f32x16 acc[4] = {};
  float m = -3.0e38f, lsum = 0.f;

  const unsigned short* kbase = K + (long)(b * SEQ) * NKVD + kv * HDIM + 8 * hi;
  const unsigned short* vbase = Vt + (long)(kv * HDIM) * MROWS + (long)b * SEQ + 8 * hi;

  // K prologue: tile 0 fragments into registers
  bf16x8 kf[8];
  {
    const unsigned short* kr = kbase + (long)lq * NKVD;
#pragma unroll
    for (int ks = 0; ks < 8; ++ks) kf[ks] = *(const bf16x8*)(kr + ks * 16);
  }

#pragma unroll 2
  for (int kt = 0; kt < SEQ; kt += 32) {
    // V prefetch for THIS tile (independent of scores; hides under QK^T+softmax)
    bf16x8 vf[8];
#pragma unroll
    for (int db = 0; db < 4; ++db) {
      const unsigned short* vr = vbase + (long)(db * 32 + lq) * MROWS + kt;
      vf[2 * db]     = *(const bf16x8*)(vr);
      vf[2 * db + 1] = *(const bf16x8*)(vr + 16);
    }

    // S^T = K·Q^T for this tile
    f32x16 s = {};
#pragma unroll
    for (int ks = 0; ks < 8; ++ks)
      s = __builtin_amdgcn_mfma_f32_32x32x16_bf16(kf[ks], qf[ks], s, 0, 0, 0);

    // NEXT-tile K prefetch (wraps at end; hides under softmax+PV)
    {
      const unsigned short* kr = kbase + (long)(((kt + 32) & (SEQ - 1)) + lq) * NKVD;
#pragma unroll
      for (int ks = 0; ks < 8; ++ks) kf[ks] = *(const bf16x8*)(kr + ks * 16);
    }

    // online softmax
    float t0 = fmaxf(fmaxf(s[0], s[1]), fmaxf(s[2], s[3]));
    float t1 = fmaxf(fmaxf(s[4], s[5]), fmaxf(s[6], s[7]));
    float t2 = fmaxf(fmaxf(s[8], s[9]), fmaxf(s[10], s[11]));
    float t3 = fmaxf(fmaxf(s[12], s[13]), fmaxf(s[14], s[15]));
    float rm = fmaxf(fmaxf(t0, t1), fmaxf(t2, t3));
    rm = fmaxf(rm, __shfl_xor(rm, 32, 64));

    // defer-max (T13): rescale only when max grew by > 8 (log2 domain)
    if (__any(rm > m + 8.0f)) {
      float mn = fmaxf(m, rm);
      float corr = exp2f(m - mn);
      m = mn;
      lsum *= corr;
      cl[w][lq] = corr;
      float cc[16];
#pragma unroll
      for (int r = 0; r < 16; ++r)
        cc[r] = cl[w][(r & 3) + 8 * (r >> 2) + 4 * hi];
#pragma unroll
      for (int db = 0; db < 4; ++db)
#pragma unroll
        for (int r = 0; r < 16; ++r) acc[db][r] *= cc[r];
    }

    float p[16];
    float ps = 0.f;
#pragma unroll
    for (int r = 0; r < 16; ++r) { p[r] = exp2f(s[r] - m); ps += p[r]; }
    lsum += ps + __shfl_xor(ps, 32, 64);

    // T12: pack P into PV A-fragments (cvt_pk + permlane32_swap)
    bf16x8 pa[2];
#pragma unroll
    for (int c = 0; c < 2; ++c) {
      unsigned a0 = cvtpk_bf16(p[8 * c + 0], p[8 * c + 1]);
      unsigned b0 = cvtpk_bf16(p[8 * c + 4], p[8 * c + 5]);
      unsigned a1 = cvtpk_bf16(p[8 * c + 2], p[8 * c + 3]);
      unsigned b1 = cvtpk_bf16(p[8 * c + 6], p[8 * c + 7]);
      asm("v_permlane32_swap_b32 %0, %1" : "+v"(a0), "+v"(b0));
      asm("v_permlane32_swap_b32 %0, %1" : "+v"(a1), "+v"(b1));
      u32x4 w4 = {a0, a1, b0, b1};
      pa[c] = __builtin_bit_cast(bf16x8, w4);
    }

    // PV with prefetched V registers
#pragma unroll
    for (int db = 0; db < 4; ++db) {
      acc[db] = __builtin_amdgcn_mfma_f32_32x32x16_bf16(pa[0], vf[2 * db],     acc[db], 0, 0, 0);
      acc[db] = __builtin_amdgcn_mfma_f32_32x32x16_bf16(pa[1], vf[2 * db + 1], acc[db], 0, 0, 0);
    }
  }

  float il = 1.0f / lsum;
  cl[w][lq] = il;
  float ic[16];
#pragma unroll
  for (int r = 0; r < 16; ++r)
    ic[r] = cl[w][(r & 3) + 8 * (r >> 2) + 4 * hi];
#pragma unroll
  for (int db = 0; db < 4; ++db)
#pragma unroll
    for (int r = 0; r < 16; ++r) {
      int row = (r & 3) + 8 * (r >> 2) + 4 * hi;
      O[(long)(b * SEQ + q0 + row) * HID + h * HDIM + db * 32 + lq] =
          f2bf(acc[db][r] * ic[r]);
    }
}

// ------------------------------------------------------------------- launcher
extern "C" void kernel_launch(void* const* d_in, const int* in_sizes, int n_in,
                              void* d_out, int out_size, void* d_ws, size_t ws_size,
                              hipStream_t stream) {
  (void)in_sizes; (void)n_in; (void)out_size; (void)ws_size;
  const int*   positions = (const int*)d_in[0];
  const float* hs = (const float*)d_in[1];
  const float* wq = (const float*)d_in[2];
  const float* wk = (const float*)d_in[3];
  const float* wv = (const float*)d_in[4];
  const float* wo = (const float*)d_in[5];
  const float* qw = (const float*)d_in[6];
  const float* kw = (const float*)d_in[7];

  char* ws = (char*)d_ws;                                   // 160 MB total
  unsigned short* hs_b = (unsigned short*)(ws);              // 32 MB
  unsigned short* wq_b = (unsigned short*)(ws + 33554432);   // 32 MB (reused as attn-out)
  unsigned short* wk_b = (unsigned short*)(ws + 67108864);   //  8 MB
  unsigned short* wv_b = (unsigned short*)(ws + 75497472);   //  8 MB
  unsigned short* wo_b = (unsigned short*)(ws + 83886080);   // 32 MB
  unsigned short* q_b  = (unsigned short*)(ws + 117440512);  // 32 MB
  unsigned short* k_b  = (unsigned short*)(ws + 150994944);  //  8 MB
  unsigned short* vt_b = (unsigned short*)(ws + 159383552);  //  8 MB
  unsigned short* ao_b = wq_b;  // wq dead after Q-proj; alias for attention out

  // f32 -> bf16 conversions
  cvt_kernel<<<dim3((16777216 / 8 + 255) / 256), dim3(256), 0, stream>>>(hs, hs_b, 16777216 / 8);
  cvt_kernel<<<dim3((16777216 / 8 + 255) / 256), dim3(256), 0, stream>>>(wq, wq_b, 16777216 / 8);
  cvt_kernel<<<dim3((4194304 / 8 + 255) / 256), dim3(256), 0, stream>>>(wk, wk_b, 4194304 / 8);
  cvt_kernel<<<dim3((4194304 / 8 + 255) / 256), dim3(256), 0, stream>>>(wv, wv_b, 4194304 / 8);
  cvt_kernel<<<dim3((16777216 / 8 + 255) / 256), dim3(256), 0, stream>>>(wo, wo_b, 16777216 / 8);

  // projections: Q via 8-phase 256² template; K/V via 128² template
  gemm8_bt<0><<<dim3(256), dim3(512), 0, stream>>>(hs_b, wq_b, q_b);
  gemm_bt<0><<<dim3(8, 32), dim3(256), 0, stream>>>(hs_b, wk_b, k_b, 4096, 1024, 4096, 1024);
  gemm_bt<2><<<dim3(8, 32), dim3(256), 0, stream>>>(hs_b, wv_b, vt_b, 4096, 1024, 4096, 4096);

  // per-head RMSNorm + RoPE (in place)
  normrope_kernel<<<dim3(32768), dim3(256), 0, stream>>>(q_b, qw, positions, 5, 4096);
  normrope_kernel<<<dim3(8192), dim3(256), 0, stream>>>(k_b, kw, positions, 3, 1024);

  // attention (32x32 swapped structure): 4b x 32h x 8 q-blocks = 1024 blocks
  attn_kernel<<<dim3(1024), dim3(256), 0, stream>>>(q_b, k_b, vt_b, ao_b);

  // output projection -> f32 d_out (8-phase 256² template)
  gemm8_bt<1><<<dim3(256), dim3(512), 0, stream>>>(ao_b, wo_b, (float*)d_out);
}

// Round 7
// 588.019 us; speedup vs baseline: 1.7641x; 1.2004x over previous
//
#include <hip/hip_runtime.h>
#include <math.h>

// Problem constants (B=4, S=1024, HIDDEN=4096, H=32, KV=8, D=128)
#define SEQ    1024
#define BATCH  4
#define MROWS  4096          // B*S
#define HID    4096
#define NHEADS 32
#define NKV    8
#define HDIM   128

typedef __bf16 bf16x8 __attribute__((ext_vector_type(8)));
typedef float  f32x4  __attribute__((ext_vector_type(4)));
typedef float  f32x16 __attribute__((ext_vector_type(16)));
typedef unsigned short u16x8 __attribute__((ext_vector_type(8)));
typedef unsigned short u16x4 __attribute__((ext_vector_type(4)));
typedef unsigned int   u32x4 __attribute__((ext_vector_type(4)));

static __device__ __forceinline__ unsigned short f2bf(float f) {
  union { float f; unsigned u; } x; x.f = f;
  unsigned r = x.u + 0x7fffu + ((x.u >> 16) & 1u);   // RNE
  return (unsigned short)(r >> 16);
}
static __device__ __forceinline__ float bf2f(unsigned short h) {
  union { unsigned u; float f; } x; x.u = ((unsigned)h) << 16;
  return x.f;
}
static __device__ __forceinline__ unsigned cvtpk_bf16(float lo, float hi) {
  unsigned r;
  asm("v_cvt_pk_bf16_f32 %0, %1, %2" : "=v"(r) : "v"(lo), "v"(hi));
  return r;
}

// async global->LDS, 16B per lane; LDS dest is wave-uniform base + lane*16
static __device__ __forceinline__ void gload16(const unsigned short* g, unsigned short* l) {
  __builtin_amdgcn_global_load_lds(
      (const __attribute__((address_space(1))) unsigned int*)g,
      (__attribute__((address_space(3))) unsigned int*)l, 16, 0, 0);
}

// ---------------------------------------------------------------- f32 -> bf16
__global__ __launch_bounds__(256) void cvt_kernel(const float* __restrict__ in,
                                                  unsigned short* __restrict__ out,
                                                  int n8) {
  int i = blockIdx.x * 256 + threadIdx.x;
  if (i >= n8) return;
  f32x4 a = ((const f32x4*)in)[2 * i];
  f32x4 b = ((const f32x4*)in)[2 * i + 1];
  u16x8 o;
  o[0] = f2bf(a[0]); o[1] = f2bf(a[1]); o[2] = f2bf(a[2]); o[3] = f2bf(a[3]);
  o[4] = f2bf(b[0]); o[5] = f2bf(b[1]); o[6] = f2bf(b[2]); o[7] = f2bf(b[3]);
  ((u16x8*)out)[i] = o;
}

// ------------------------------------------------------- C = A * B^T (128² tile)
// OUTMODE: 0 = bf16 C[M][N]; 1 = f32 C[M][N];
//          3 = V-tile layout for attention staging:
//              tiles[b][kv][kt32][d128][k32], chunk-swizzled
//              (elem (d,k) at d*32 + ((k>>3)^((d^(d>>2))&3))*8 + (k&7))
template <int OUTMODE>
__global__ __launch_bounds__(256) void gemm_bt(const unsigned short* __restrict__ A,
                                               const unsigned short* __restrict__ B,
                                               void* __restrict__ Cp,
                                               int M, int N, int K, int ldc) {
  __shared__ unsigned short As[4096];   // [128][32]
  __shared__ unsigned short Bs[4096];
  const int t  = threadIdx.x;
  const int l  = t & 63, w = t >> 6;
  const int wr = w >> 1, wc = w & 1;
  const int lr = l & 15, lg = l >> 4;
  const int m0 = blockIdx.y * 128, n0 = blockIdx.x * 128;

  const int srow = t >> 2;
  const int skg  = (t & 3) ^ (srow & 3);
  const unsigned short* ga0 = A + (long)(m0 + srow) * K + skg * 8;
  const unsigned short* ga1 = ga0 + 64L * K;
  const unsigned short* gb0 = B + (long)(n0 + srow) * K + skg * 8;
  const unsigned short* gb1 = gb0 + 64L * K;

  int aro[4], bro[4];
#pragma unroll
  for (int i = 0; i < 4; ++i) {
    aro[i] = (wr * 64 + i * 16 + lr) * 32 + ((lg ^ (lr & 3)) * 8);
    bro[i] = (wc * 64 + i * 16 + lr) * 32 + ((lg ^ (lr & 3)) * 8);
  }

  f32x4 acc[4][4] = {};
  for (int k0 = 0; k0 < K; k0 += 32) {
    if (k0) __syncthreads();
    gload16(ga0 + k0, As + (w << 9));
    gload16(ga1 + k0, As + 2048 + (w << 9));
    gload16(gb0 + k0, Bs + (w << 9));
    gload16(gb1 + k0, Bs + 2048 + (w << 9));
    __syncthreads();
    bf16x8 af[4], bfv[4];
#pragma unroll
    for (int i = 0; i < 4; ++i) af[i]  = *(const bf16x8*)(As + aro[i]);
#pragma unroll
    for (int i = 0; i < 4; ++i) bfv[i] = *(const bf16x8*)(Bs + bro[i]);
#pragma unroll
    for (int mi = 0; mi < 4; ++mi)
#pragma unroll
      for (int ni = 0; ni < 4; ++ni)
        acc[mi][ni] = __builtin_amdgcn_mfma_f32_16x16x32_bf16(af[mi], bfv[ni],
                                                              acc[mi][ni], 0, 0, 0);
  }

  const int r0 = m0 + wr * 64 + lg * 4;
  const int c0 = n0 + wc * 64 + lr;
  if (OUTMODE == 0) {
    unsigned short* C = (unsigned short*)Cp;
#pragma unroll
    for (int mi = 0; mi < 4; ++mi)
#pragma unroll
      for (int ni = 0; ni < 4; ++ni)
#pragma unroll
        for (int j = 0; j < 4; ++j)
          C[(long)(r0 + mi * 16 + j) * ldc + (c0 + ni * 16)] = f2bf(acc[mi][ni][j]);
  } else if (OUTMODE == 1) {
    float* C = (float*)Cp;
#pragma unroll
    for (int mi = 0; mi < 4; ++mi)
#pragma unroll
      for (int ni = 0; ni < 4; ++ni)
#pragma unroll
        for (int j = 0; j < 4; ++j)
          C[(long)(r0 + mi * 16 + j) * ldc + (c0 + ni * 16)] = acc[mi][ni][j];
  } else {
    // OUTMODE 3: V tiles, swizzled. M-rows = s, N-cols = d_global = kv*128+d.
    unsigned short* C = (unsigned short*)Cp;
#pragma unroll
    for (int mi = 0; mi < 4; ++mi)
#pragma unroll
      for (int ni = 0; ni < 4; ++ni) {
        const int s_g   = r0 + mi * 16;            // 4 consecutive s (j=0..3)
        const int d_g   = c0 + ni * 16;
        const int bb    = s_g >> 10;
        const int s_loc = s_g & 1023;
        const int kt_i  = s_loc >> 5;
        const int k_loc = s_loc & 31;              // ≡0 mod 4 → same 8B slot
        const int kvh   = d_g >> 7;
        const int d_loc = d_g & 127;
        const int fxor  = (d_loc ^ (d_loc >> 2)) & 3;
        const long addr = ((long)((bb * NKV + kvh) * 32 + kt_i)) * 4096 +
                          d_loc * 32 + (((k_loc >> 3) ^ fxor) << 3) + (k_loc & 7);
        u16x4 v;
#pragma unroll
        for (int j = 0; j < 4; ++j) v[j] = f2bf(acc[mi][ni][j]);
        *(u16x4*)(C + addr) = v;
      }
  }
}

// ---------------------------------------------- 256² 8-phase GEMM (T2+T3+T4+T5)
// (unchanged from R4 — verified: ~95 µs per 4096³, pass)
#define BAR8 __builtin_amdgcn_s_barrier()
#define WL0  do { asm volatile("s_waitcnt lgkmcnt(0)" ::: "memory"); \
                  __builtin_amdgcn_sched_barrier(0); } while (0)
#define WV6  asm volatile("s_waitcnt vmcnt(6)" ::: "memory")

template <int OUTMODE>
__global__ __launch_bounds__(512, 2) void gemm8_bt(const unsigned short* __restrict__ A,
                                                   const unsigned short* __restrict__ B,
                                                   void* __restrict__ Cp) {
  __shared__ unsigned short lds[65536];        // 128 KiB
  const int t = threadIdx.x, l = t & 63, w = t >> 6;
  const int wr = w >> 2, wc = w & 3;
  const int lr = l & 15, lg = l >> 4;
  const int bid = blockIdx.x;
  const int swz = (bid & 7) * 32 + (bid >> 3);  // XCD swizzle (256 % 8 == 0)
  const int m0 = (swz >> 4) << 8, n0 = (swz & 15) << 8;
  const long K = 4096;

  const int rc = l >> 3;
  const int ce = ((l & 7) ^ rc) << 3;

#define STGA(d, h, tt) do { \
    const unsigned short* _s = A + (long)(m0 + (h)*128 + w*8 + rc) * K + (long)(tt)*64 + ce; \
    gload16(_s,            lds + ((d)*2+(h))*8192 + w*512); \
    gload16(_s + 64L * K,  lds + ((d)*2+(h))*8192 + (8 + w)*512); \
  } while (0)
#define STGB(d, h, tt) do { \
    const unsigned short* _s = B + (long)(n0 + (h)*128 + w*8 + rc) * K + (long)(tt)*64 + ce; \
    gload16(_s,            lds + 32768 + ((d)*2+(h))*8192 + w*512); \
    gload16(_s + 64L * K,  lds + 32768 + ((d)*2+(h))*8192 + (8 + w)*512); \
  } while (0)
#define LDA8(d, rh) do { \
    _Pragma("unroll") for (int ri = 0; ri < 4; ++ri) \
    _Pragma("unroll") for (int kk = 0; kk < 2; ++kk) { \
      int r  = wr*64 + ri*16 + lr; \
      int cb = (kk*64 + lg*16) ^ ((l & 7) << 4); \
      a[ri][kk] = *(const bf16x8*)(lds + ((d)*2+(rh))*8192 + r*64 + (cb >> 1)); \
    } } while (0)
#define LDB8(d, ch, barr) do { \
    _Pragma("unroll") for (int ci = 0; ci < 2; ++ci) \
    _Pragma("unroll") for (int kk = 0; kk < 2; ++kk) { \
      int r  = wc*32 + ci*16 + lr; \
      int cb = (kk*64 + lg*16) ^ ((l & 7) << 4); \
      barr[ci][kk] = *(const bf16x8*)(lds + 32768 + ((d)*2+(ch))*8192 + r*64 + (cb >> 1)); \
    } } while (0)
#define MM8(rh, ch, barr) do { \
    __builtin_amdgcn_s_setprio(1); \
    _Pragma("unroll") for (int kk = 0; kk < 2; ++kk) \
    _Pragma("unroll") for (int ri = 0; ri < 4; ++ri) \
    _Pragma("unroll") for (int ci = 0; ci < 2; ++ci) \
      acc[rh][ch][ri][ci] = __builtin_amdgcn_mfma_f32_16x16x32_bf16( \
          a[ri][kk], barr[ci][kk], acc[rh][ch][ri][ci], 0, 0, 0); \
    __builtin_amdgcn_s_setprio(0); \
  } while (0)

  f32x4 acc[2][2][4][2] = {};
  bf16x8 a[4][2], b0[2][2], b1[2][2];

  STGA(0, 0, 0); STGB(0, 0, 0); STGB(0, 1, 0); STGA(0, 1, 0);
  STGA(1, 0, 1); STGB(1, 0, 1); STGB(1, 1, 1);
  WV6;
  BAR8;

  for (int i = 0; i < 32; ++i) {
    const int t1 = 2 * i + 1, t2 = (2 * i + 2) & 63, t3 = (2 * i + 3) & 63;
    LDA8(0, 0); LDB8(0, 0, b0);
    STGA(1, 1, t1);
    BAR8; WL0; MM8(0, 0, b0); BAR8;
    LDB8(0, 1, b1);
    STGA(0, 0, t2);
    BAR8; WL0; MM8(0, 1, b1); BAR8;
    LDA8(0, 1);
    STGB(0, 0, t2);
    BAR8; WL0; MM8(1, 1, b1); BAR8;
    STGB(0, 1, t2);
    WV6;
    BAR8; WL0; MM8(1, 0, b0); BAR8;
    LDA8(1, 0); LDB8(1, 0, b0);
    STGA(0, 1, t2);
    BAR8; WL0; MM8(0, 0, b0); BAR8;
    LDB8(1, 1, b1);
    STGA(1, 0, t3);
    BAR8; WL0; MM8(0, 1, b1); BAR8;
    LDA8(1, 1);
    STGB(1, 0, t3);
    BAR8; WL0; MM8(1, 1, b1); BAR8;
    STGB(1, 1, t3);
    WV6;
    BAR8; WL0; MM8(1, 0, b0); BAR8;
  }

#pragma unroll
  for (int rh = 0; rh < 2; ++rh)
#pragma unroll
    for (int ch = 0; ch < 2; ++ch)
#pragma unroll
      for (int ri = 0; ri < 4; ++ri)
#pragma unroll
        for (int ci = 0; ci < 2; ++ci)
#pragma unroll
          for (int j = 0; j < 4; ++j) {
            const int row = m0 + rh * 128 + wr * 64 + ri * 16 + lg * 4 + j;
            const int col = n0 + ch * 128 + wc * 32 + ci * 16 + lr;
            if (OUTMODE == 0)
              ((unsigned short*)Cp)[(long)row * 4096 + col] = f2bf(acc[rh][ch][ri][ci][j]);
            else
              ((float*)Cp)[(long)row * 4096 + col] = acc[rh][ch][ri][ci][j];
          }
#undef STGA
#undef STGB
#undef LDA8
#undef LDB8
#undef MM8
}

// --------------------------------------------- fused per-head RMSNorm + RoPE
__global__ __launch_bounds__(256) void normrope_kernel(unsigned short* __restrict__ X,
                                                       const float* __restrict__ wnorm,
                                                       const int* __restrict__ positions,
                                                       int hshift, int stride) {
  const int t = threadIdx.x, l = t & 63, wv = t >> 6;
  const int slice = blockIdx.x * 4 + wv;
  const int head  = slice & ((1 << hshift) - 1);
  const int row   = slice >> hshift;
  const int s     = row & (SEQ - 1);
  unsigned short* p = X + (long)row * stride + (head << 7);

  float x1 = bf2f(p[l]), x2 = bf2f(p[l + 64]);
  float ss = x1 * x1 + x2 * x2;
#pragma unroll
  for (int m = 1; m < 64; m <<= 1) ss += __shfl_xor(ss, m, 64);
  float inv = rsqrtf(ss * (1.0f / 128.0f) + 1e-6f);
  x1 *= inv * wnorm[l];
  x2 *= inv * wnorm[l + 64];

  float invf = exp2f((float)l * -0.31143075889569023f);
  float ang  = (float)positions[s] * invf;
  float sn, cs;
  sincosf(ang, &sn, &cs);
  p[l]      = f2bf(x1 * cs - x2 * sn);
  p[l + 64] = f2bf(x2 * cs + x1 * sn);
}

// ------------------------------------------------------------ flash attention
// 32x32 swapped-QK^T + cooperative LDS staging (T2+T3+T4+T5):
//   K,V staged per 32-key tile via global_load_lds into a ring-3 LDS buffer,
//   counted vmcnt(4) keeps 2 tiles in flight; XOR-swizzled stage/read pair
//   (K: chunk^=(row&15); V pre-swizzled by the producer GEMM). One barrier
//   per iteration (ring-3 reuse distance: tile ti+2 overwrites the slot last
//   read at ti-1, whose reads retired before barrier@ti).
__global__ __launch_bounds__(256, 3) void attn_kernel(const unsigned short* __restrict__ Q,
                                                      const unsigned short* __restrict__ Kb,
                                                      const unsigned short* __restrict__ Vtl,
                                                      unsigned short* __restrict__ O) {
  __shared__ unsigned short lds[24576];   // 48 KiB: K rings [0,12288), V rings [12288,24576)
  __shared__ float cl[4][32];
  const int t = threadIdx.x, l = t & 63, w = t >> 6;
  const int lq = l & 31, hi = l >> 5;
  const int blk = blockIdx.x;
  const int qb = blk & 7, h = (blk >> 3) & 31, b = blk >> 8;
  const int kv = h >> 2;                     // GQA: 4 q-heads per kv-head
  const int q0 = qb * 128 + w * 32;

  // Q as B-fragments, (1/sqrt(128))*log2(e) folded in
  const float qsc = 0.12751791438584222f;
  bf16x8 qf[8];
  const unsigned short* qrow = Q + (long)(b * SEQ + q0 + lq) * HID + h * HDIM + 8 * hi;
#pragma unroll
  for (int ks = 0; ks < 8; ++ks) {
    u16x8 raw = *(const u16x8*)(qrow + ks * 16);
    bf16x8 qv;
#pragma unroll
    for (int j = 0; j < 8; ++j) qv[j] = (__bf16)(bf2f(raw[j]) * qsc);
    qf[ks] = qv;
  }

  const unsigned short* Kg = Kb + (long)(b * SEQ) * 1024 + kv * HDIM;
  const unsigned short* Vg = Vtl + (long)(b * NKV + kv) * 32 * 4096;

  // stage: 8KB/tile each for K and V; 256 threads x 2 gload16 each.
  // K slot s: LDS row s>>4, chunk s&15; source chunk ^= row&15 (both-sides swz)
#define STG_K(ring, ti) do { \
    _Pragma("unroll") for (int rr = 0; rr < 2; ++rr) { \
      int _row = (rr * 4 + w) * 4 + (l >> 4); \
      int _sc  = (l & 15) ^ (_row & 15); \
      gload16(Kg + (long)((ti) * 32 + _row) * 1024 + (_sc << 3), \
              lds + (ring) * 4096 + (rr * 4 + w) * 512); \
    } } while (0)
#define STG_V(ring, ti) do { \
    _Pragma("unroll") for (int rr = 0; rr < 2; ++rr) \
      gload16(Vg + (long)(ti) * 4096 + (((rr * 4 + w) * 64 + l) << 3), \
              lds + 12288 + (ring) * 4096 + (rr * 4 + w) * 512); \
    } while (0)

  f32x16 acc[4] = {};
  float m = -3.0e38f, lsum = 0.f;

  // prologue: tiles 0,1 into rings 0,1 (4 gload16/thread/tile)
  STG_K(0, 0); STG_V(0, 0);
  STG_K(1, 1); STG_V(1, 1);

  int ring = 0;
  for (int ti = 0; ti < 32; ++ti) {
    // tile ti landed (own 4 oldest DMAs), then block-wide barrier
    asm volatile("s_waitcnt vmcnt(4)" ::: "memory");
    __builtin_amdgcn_s_barrier();
    __builtin_amdgcn_sched_barrier(0);

    // stage tile ti+2 (ring (ti+2)%3; overwrites data last read at ti-1)
    const int rstage = (ring >= 1) ? ring - 1 : 2;
    const int tn = (ti + 2) & 31;
    STG_K(rstage, tn); STG_V(rstage, tn);

    // QK^T: lane holds 16 keys of q-row lq
    const unsigned short* kb = lds + ring * 4096 + lq * 128;
    bf16x8 kf[8];
#pragma unroll
    for (int ks = 0; ks < 8; ++ks)
      kf[ks] = *(const bf16x8*)(kb + ((((ks << 1) + hi) ^ (lq & 15)) << 3));
    f32x16 s = {};
    __builtin_amdgcn_s_setprio(1);
#pragma unroll
    for (int ks = 0; ks < 8; ++ks)
      s = __builtin_amdgcn_mfma_f32_32x32x16_bf16(kf[ks], qf[ks], s, 0, 0, 0);
    __builtin_amdgcn_s_setprio(0);

    // online softmax
    float t0 = fmaxf(fmaxf(s[0], s[1]), fmaxf(s[2], s[3]));
    float t1 = fmaxf(fmaxf(s[4], s[5]), fmaxf(s[6], s[7]));
    float t2 = fmaxf(fmaxf(s[8], s[9]), fmaxf(s[10], s[11]));
    float t3 = fmaxf(fmaxf(s[12], s[13]), fmaxf(s[14], s[15]));
    float rm = fmaxf(fmaxf(t0, t1), fmaxf(t2, t3));
    rm = fmaxf(rm, __shfl_xor(rm, 32, 64));

    if (__any(rm > m + 8.0f)) {        // T13 defer-max
      float mn = fmaxf(m, rm);
      float corr = exp2f(m - mn);
      m = mn;
      lsum *= corr;
      cl[w][lq] = corr;
      float cc[16];
#pragma unroll
      for (int r = 0; r < 16; ++r)
        cc[r] = cl[w][(r & 3) + 8 * (r >> 2) + 4 * hi];
#pragma unroll
      for (int db = 0; db < 4; ++db)
#pragma unroll
        for (int r = 0; r < 16; ++r) acc[db][r] *= cc[r];
    }

    float p[16];
    float ps = 0.f;
#pragma unroll
    for (int r = 0; r < 16; ++r) { p[r] = exp2f(s[r] - m); ps += p[r]; }
    lsum += ps + __shfl_xor(ps, 32, 64);

    // T12: pack P into PV A-fragments
    bf16x8 pa[2];
#pragma unroll
    for (int c = 0; c < 2; ++c) {
      unsigned a0 = cvtpk_bf16(p[8 * c + 0], p[8 * c + 1]);
      unsigned b0 = cvtpk_bf16(p[8 * c + 4], p[8 * c + 5]);
      unsigned a1 = cvtpk_bf16(p[8 * c + 2], p[8 * c + 3]);
      unsigned b1 = cvtpk_bf16(p[8 * c + 6], p[8 * c + 7]);
      asm("v_permlane32_swap_b32 %0, %1" : "+v"(a0), "+v"(b0));
      asm("v_permlane32_swap_b32 %0, %1" : "+v"(a1), "+v"(b1));
      u32x4 w4 = {a0, a1, b0, b1};
      pa[c] = __builtin_bit_cast(bf16x8, w4);
    }

    // PV from V ring (swizzled [d][k32] tile)
    __builtin_amdgcn_s_setprio(1);
#pragma unroll
    for (int db = 0; db < 4; ++db) {
      const int row = db * 32 + lq;
      const int fx  = (row ^ (row >> 2)) & 3;
      const unsigned short* vb = lds + 12288 + ring * 4096 + row * 32;
      bf16x8 v0 = *(const bf16x8*)(vb + ((hi ^ fx) << 3));
      bf16x8 v1 = *(const bf16x8*)(vb + (((2 + hi) ^ fx) << 3));
      acc[db] = __builtin_amdgcn_mfma_f32_32x32x16_bf16(pa[0], v0, acc[db], 0, 0, 0);
      acc[db] = __builtin_amdgcn_mfma_f32_32x32x16_bf16(pa[1], v1, acc[db], 0, 0, 0);
    }
    __builtin_amdgcn_s_setprio(0);

    ring = (ring < 2) ? ring + 1 : 0;
  }
#undef STG_K
#undef STG_V

  float il = 1.0f / lsum;
  cl[w][lq] = il;
  float ic[16];
#pragma unroll
  for (int r = 0; r < 16; ++r)
    ic[r] = cl[w][(r & 3) + 8 * (r >> 2) + 4 * hi];
#pragma unroll
  for (int db = 0; db < 4; ++db)
#pragma unroll
    for (int r = 0; r < 16; ++r) {
      int row = (r & 3) + 8 * (r >> 2) + 4 * hi;
      O[(long)(b * SEQ + q0 + row) * HID + h * HDIM + db * 32 + lq] =
          f2bf(acc[db][r] * ic[r]);
    }
}

// ------------------------------------------------------------------- launcher
extern "C" void kernel_launch(void* const* d_in, const int* in_sizes, int n_in,
                              void* d_out, int out_size, void* d_ws, size_t ws_size,
                              hipStream_t stream) {
  (void)in_sizes; (void)n_in; (void)out_size; (void)ws_size;
  const int*   positions = (const int*)d_in[0];
  const float* hs = (const float*)d_in[1];
  const float* wq = (const float*)d_in[2];
  const float* wk = (const float*)d_in[3];
  const float* wv = (const float*)d_in[4];
  const float* wo = (const float*)d_in[5];
  const float* qw = (const float*)d_in[6];
  const float* kw = (const float*)d_in[7];

  char* ws = (char*)d_ws;                                   // 160 MB total
  unsigned short* hs_b = (unsigned short*)(ws);              // 32 MB
  unsigned short* wq_b = (unsigned short*)(ws + 33554432);   // 32 MB (reused as attn-out)
  unsigned short* wk_b = (unsigned short*)(ws + 67108864);   //  8 MB
  unsigned short* wv_b = (unsigned short*)(ws + 75497472);   //  8 MB
  unsigned short* wo_b = (unsigned short*)(ws + 83886080);   // 32 MB
  unsigned short* q_b  = (unsigned short*)(ws + 117440512);  // 32 MB
  unsigned short* k_b  = (unsigned short*)(ws + 150994944);  //  8 MB
  unsigned short* vt_b = (unsigned short*)(ws + 159383552);  //  8 MB (V tiles)
  unsigned short* ao_b = wq_b;  // wq dead after Q-proj; alias for attention out

  // f32 -> bf16 conversions
  cvt_kernel<<<dim3((16777216 / 8 + 255) / 256), dim3(256), 0, stream>>>(hs, hs_b, 16777216 / 8);
  cvt_kernel<<<dim3((16777216 / 8 + 255) / 256), dim3(256), 0, stream>>>(wq, wq_b, 16777216 / 8);
  cvt_kernel<<<dim3((4194304 / 8 + 255) / 256), dim3(256), 0, stream>>>(wk, wk_b, 4194304 / 8);
  cvt_kernel<<<dim3((4194304 / 8 + 255) / 256), dim3(256), 0, stream>>>(wv, wv_b, 4194304 / 8);
  cvt_kernel<<<dim3((16777216 / 8 + 255) / 256), dim3(256), 0, stream>>>(wo, wo_b, 16777216 / 8);

  // projections: Q via 8-phase 256² template; K via 128²; V -> swizzled tiles
  gemm8_bt<0><<<dim3(256), dim3(512), 0, stream>>>(hs_b, wq_b, q_b);
  gemm_bt<0><<<dim3(8, 32), dim3(256), 0, stream>>>(hs_b, wk_b, k_b, 4096, 1024, 4096, 1024);
  gemm_bt<3><<<dim3(8, 32), dim3(256), 0, stream>>>(hs_b, wv_b, vt_b, 4096, 1024, 4096, 0);

  // per-head RMSNorm + RoPE (in place; K normed in k_b before attn stages it)
  normrope_kernel<<<dim3(32768), dim3(256), 0, stream>>>(q_b, qw, positions, 5, 4096);
  normrope_kernel<<<dim3(8192), dim3(256), 0, stream>>>(k_b, kw, positions, 3, 1024);

  // attention: 4b x 32h x 8 q-blocks = 1024 blocks, LDS-staged K/V
  attn_kernel<<<dim3(1024), dim3(256), 0, stream>>>(q_b, k_b, vt_b, ao_b);

  // output projection -> f32 d_out (8-phase 256² template)
  gemm8_bt<1><<<dim3(256), dim3(512), 0, stream>>>(ao_b, wo_b, (float*)d_out);
}

// Round 8
// 568.751 us; speedup vs baseline: 1.8238x; 1.0339x over previous
//
#include <hip/hip_runtime.h>
#include <math.h>

// Problem constants (B=4, S=1024, HIDDEN=4096, H=32, KV=8, D=128)
#define SEQ    1024
#define BATCH  4
#define MROWS  4096          // B*S
#define HID    4096
#define NHEADS 32
#define NKV    8
#define HDIM   128

typedef __bf16 bf16x8 __attribute__((ext_vector_type(8)));
typedef float  f32x4  __attribute__((ext_vector_type(4)));
typedef float  f32x16 __attribute__((ext_vector_type(16)));
typedef unsigned short u16x8 __attribute__((ext_vector_type(8)));
typedef unsigned short u16x4 __attribute__((ext_vector_type(4)));
typedef unsigned int   u32x4 __attribute__((ext_vector_type(4)));

static __device__ __forceinline__ unsigned short f2bf(float f) {
  union { float f; unsigned u; } x; x.f = f;
  unsigned r = x.u + 0x7fffu + ((x.u >> 16) & 1u);   // RNE
  return (unsigned short)(r >> 16);
}
static __device__ __forceinline__ float bf2f(unsigned short h) {
  union { unsigned u; float f; } x; x.u = ((unsigned)h) << 16;
  return x.f;
}
static __device__ __forceinline__ unsigned cvtpk_bf16(float lo, float hi) {
  unsigned r;
  asm("v_cvt_pk_bf16_f32 %0, %1, %2" : "=v"(r) : "v"(lo), "v"(hi));
  return r;
}

// async global->LDS, 16B per lane; LDS dest is wave-uniform base + lane*16
static __device__ __forceinline__ void gload16(const unsigned short* g, unsigned short* l) {
  __builtin_amdgcn_global_load_lds(
      (const __attribute__((address_space(1))) unsigned int*)g,
      (__attribute__((address_space(3))) unsigned int*)l, 16, 0, 0);
}

// ------------------------------------------------- fused f32 -> bf16 (all 5 inputs)
// segments in 256-thread blocks of 8 f32 each: hs 8192 | wq 8192 | wk 2048 |
// wv 2048 | wo 8192  (all sizes divide evenly)
__global__ __launch_bounds__(256) void cvt_all(const float* __restrict__ hs,
                                               const float* __restrict__ wq,
                                               const float* __restrict__ wk,
                                               const float* __restrict__ wv,
                                               const float* __restrict__ wo,
                                               unsigned short* __restrict__ hs_b,
                                               unsigned short* __restrict__ wq_b,
                                               unsigned short* __restrict__ wk_b,
                                               unsigned short* __restrict__ wv_b,
                                               unsigned short* __restrict__ wo_b) {
  const int bid = blockIdx.x;
  const float* in; unsigned short* out; int base;
  if (bid < 8192)       { in = hs; out = hs_b; base = 0; }
  else if (bid < 16384) { in = wq; out = wq_b; base = 8192; }
  else if (bid < 18432) { in = wk; out = wk_b; base = 16384; }
  else if (bid < 20480) { in = wv; out = wv_b; base = 18432; }
  else                  { in = wo; out = wo_b; base = 20480; }
  const int i = (bid - base) * 256 + threadIdx.x;
  f32x4 a = ((const f32x4*)in)[2 * i];
  f32x4 b = ((const f32x4*)in)[2 * i + 1];
  u16x8 o;
  o[0] = f2bf(a[0]); o[1] = f2bf(a[1]); o[2] = f2bf(a[2]); o[3] = f2bf(a[3]);
  o[4] = f2bf(b[0]); o[5] = f2bf(b[1]); o[6] = f2bf(b[2]); o[7] = f2bf(b[3]);
  ((u16x8*)out)[i] = o;
}

// ------------------------------------------------------- C = A * B^T (128² tile)
// OUTMODE: 0 = bf16 C[M][N]; 1 = f32 C[M][N];
//          3 = V-tile layout for attention staging:
//              tiles[b][kv][kt32][d128][k32], chunk-swizzled
//              (elem (d,k) at d*32 + ((k>>3)^((d^(d>>2))&3))*8 + (k&7))
template <int OUTMODE>
__global__ __launch_bounds__(256) void gemm_bt(const unsigned short* __restrict__ A,
                                               const unsigned short* __restrict__ B,
                                               void* __restrict__ Cp,
                                               int M, int N, int K, int ldc) {
  __shared__ unsigned short As[4096];   // [128][32]
  __shared__ unsigned short Bs[4096];
  const int t  = threadIdx.x;
  const int l  = t & 63, w = t >> 6;
  const int wr = w >> 1, wc = w & 1;
  const int lr = l & 15, lg = l >> 4;
  const int m0 = blockIdx.y * 128, n0 = blockIdx.x * 128;

  const int srow = t >> 2;
  const int skg  = (t & 3) ^ (srow & 3);
  const unsigned short* ga0 = A + (long)(m0 + srow) * K + skg * 8;
  const unsigned short* ga1 = ga0 + 64L * K;
  const unsigned short* gb0 = B + (long)(n0 + srow) * K + skg * 8;
  const unsigned short* gb1 = gb0 + 64L * K;

  int aro[4], bro[4];
#pragma unroll
  for (int i = 0; i < 4; ++i) {
    aro[i] = (wr * 64 + i * 16 + lr) * 32 + ((lg ^ (lr & 3)) * 8);
    bro[i] = (wc * 64 + i * 16 + lr) * 32 + ((lg ^ (lr & 3)) * 8);
  }

  f32x4 acc[4][4] = {};
  for (int k0 = 0; k0 < K; k0 += 32) {
    if (k0) __syncthreads();
    gload16(ga0 + k0, As + (w << 9));
    gload16(ga1 + k0, As + 2048 + (w << 9));
    gload16(gb0 + k0, Bs + (w << 9));
    gload16(gb1 + k0, Bs + 2048 + (w << 9));
    __syncthreads();
    bf16x8 af[4], bfv[4];
#pragma unroll
    for (int i = 0; i < 4; ++i) af[i]  = *(const bf16x8*)(As + aro[i]);
#pragma unroll
    for (int i = 0; i < 4; ++i) bfv[i] = *(const bf16x8*)(Bs + bro[i]);
#pragma unroll
    for (int mi = 0; mi < 4; ++mi)
#pragma unroll
      for (int ni = 0; ni < 4; ++ni)
        acc[mi][ni] = __builtin_amdgcn_mfma_f32_16x16x32_bf16(af[mi], bfv[ni],
                                                              acc[mi][ni], 0, 0, 0);
  }

  const int r0 = m0 + wr * 64 + lg * 4;
  const int c0 = n0 + wc * 64 + lr;
  if (OUTMODE == 0) {
    unsigned short* C = (unsigned short*)Cp;
#pragma unroll
    for (int mi = 0; mi < 4; ++mi)
#pragma unroll
      for (int ni = 0; ni < 4; ++ni)
#pragma unroll
        for (int j = 0; j < 4; ++j)
          C[(long)(r0 + mi * 16 + j) * ldc + (c0 + ni * 16)] = f2bf(acc[mi][ni][j]);
  } else if (OUTMODE == 1) {
    float* C = (float*)Cp;
#pragma unroll
    for (int mi = 0; mi < 4; ++mi)
#pragma unroll
      for (int ni = 0; ni < 4; ++ni)
#pragma unroll
        for (int j = 0; j < 4; ++j)
          C[(long)(r0 + mi * 16 + j) * ldc + (c0 + ni * 16)] = acc[mi][ni][j];
  } else {
    // OUTMODE 3: V tiles, swizzled. M-rows = s, N-cols = d_global = kv*128+d.
    unsigned short* C = (unsigned short*)Cp;
#pragma unroll
    for (int mi = 0; mi < 4; ++mi)
#pragma unroll
      for (int ni = 0; ni < 4; ++ni) {
        const int s_g   = r0 + mi * 16;            // 4 consecutive s (j=0..3)
        const int d_g   = c0 + ni * 16;
        const int bb    = s_g >> 10;
        const int s_loc = s_g & 1023;
        const int kt_i  = s_loc >> 5;
        const int k_loc = s_loc & 31;              // ≡0 mod 4 → same 8B slot
        const int kvh   = d_g >> 7;
        const int d_loc = d_g & 127;
        const int fxor  = (d_loc ^ (d_loc >> 2)) & 3;
        const long addr = ((long)((bb * NKV + kvh) * 32 + kt_i)) * 4096 +
                          d_loc * 32 + (((k_loc >> 3) ^ fxor) << 3) + (k_loc & 7);
        u16x4 v;
#pragma unroll
        for (int j = 0; j < 4; ++j) v[j] = f2bf(acc[mi][ni][j]);
        *(u16x4*)(C + addr) = v;
      }
  }
}

// ---------------------------------------------- 256² 8-phase GEMM (T2+T3+T4+T5)
// (unchanged — verified: ~90 µs per 4096³, pass)
#define BAR8 __builtin_amdgcn_s_barrier()
#define WL0  do { asm volatile("s_waitcnt lgkmcnt(0)" ::: "memory"); \
                  __builtin_amdgcn_sched_barrier(0); } while (0)
#define WV6  asm volatile("s_waitcnt vmcnt(6)" ::: "memory")

template <int OUTMODE>
__global__ __launch_bounds__(512, 2) void gemm8_bt(const unsigned short* __restrict__ A,
                                                   const unsigned short* __restrict__ B,
                                                   void* __restrict__ Cp) {
  __shared__ unsigned short lds[65536];        // 128 KiB
  const int t = threadIdx.x, l = t & 63, w = t >> 6;
  const int wr = w >> 2, wc = w & 3;
  const int lr = l & 15, lg = l >> 4;
  const int bid = blockIdx.x;
  const int swz = (bid & 7) * 32 + (bid >> 3);  // XCD swizzle (256 % 8 == 0)
  const int m0 = (swz >> 4) << 8, n0 = (swz & 15) << 8;
  const long K = 4096;

  const int rc = l >> 3;
  const int ce = ((l & 7) ^ rc) << 3;

#define STGA(d, h, tt) do { \
    const unsigned short* _s = A + (long)(m0 + (h)*128 + w*8 + rc) * K + (long)(tt)*64 + ce; \
    gload16(_s,            lds + ((d)*2+(h))*8192 + w*512); \
    gload16(_s + 64L * K,  lds + ((d)*2+(h))*8192 + (8 + w)*512); \
  } while (0)
#define STGB(d, h, tt) do { \
    const unsigned short* _s = B + (long)(n0 + (h)*128 + w*8 + rc) * K + (long)(tt)*64 + ce; \
    gload16(_s,            lds + 32768 + ((d)*2+(h))*8192 + w*512); \
    gload16(_s + 64L * K,  lds + 32768 + ((d)*2+(h))*8192 + (8 + w)*512); \
  } while (0)
#define LDA8(d, rh) do { \
    _Pragma("unroll") for (int ri = 0; ri < 4; ++ri) \
    _Pragma("unroll") for (int kk = 0; kk < 2; ++kk) { \
      int r  = wr*64 + ri*16 + lr; \
      int cb = (kk*64 + lg*16) ^ ((l & 7) << 4); \
      a[ri][kk] = *(const bf16x8*)(lds + ((d)*2+(rh))*8192 + r*64 + (cb >> 1)); \
    } } while (0)
#define LDB8(d, ch, barr) do { \
    _Pragma("unroll") for (int ci = 0; ci < 2; ++ci) \
    _Pragma("unroll") for (int kk = 0; kk < 2; ++kk) { \
      int r  = wc*32 + ci*16 + lr; \
      int cb = (kk*64 + lg*16) ^ ((l & 7) << 4); \
      barr[ci][kk] = *(const bf16x8*)(lds + 32768 + ((d)*2+(ch))*8192 + r*64 + (cb >> 1)); \
    } } while (0)
#define MM8(rh, ch, barr) do { \
    __builtin_amdgcn_s_setprio(1); \
    _Pragma("unroll") for (int kk = 0; kk < 2; ++kk) \
    _Pragma("unroll") for (int ri = 0; ri < 4; ++ri) \
    _Pragma("unroll") for (int ci = 0; ci < 2; ++ci) \
      acc[rh][ch][ri][ci] = __builtin_amdgcn_mfma_f32_16x16x32_bf16( \
          a[ri][kk], barr[ci][kk], acc[rh][ch][ri][ci], 0, 0, 0); \
    __builtin_amdgcn_s_setprio(0); \
  } while (0)

  f32x4 acc[2][2][4][2] = {};
  bf16x8 a[4][2], b0[2][2], b1[2][2];

  STGA(0, 0, 0); STGB(0, 0, 0); STGB(0, 1, 0); STGA(0, 1, 0);
  STGA(1, 0, 1); STGB(1, 0, 1); STGB(1, 1, 1);
  WV6;
  BAR8;

  for (int i = 0; i < 32; ++i) {
    const int t1 = 2 * i + 1, t2 = (2 * i + 2) & 63, t3 = (2 * i + 3) & 63;
    LDA8(0, 0); LDB8(0, 0, b0);
    STGA(1, 1, t1);
    BAR8; WL0; MM8(0, 0, b0); BAR8;
    LDB8(0, 1, b1);
    STGA(0, 0, t2);
    BAR8; WL0; MM8(0, 1, b1); BAR8;
    LDA8(0, 1);
    STGB(0, 0, t2);
    BAR8; WL0; MM8(1, 1, b1); BAR8;
    STGB(0, 1, t2);
    WV6;
    BAR8; WL0; MM8(1, 0, b0); BAR8;
    LDA8(1, 0); LDB8(1, 0, b0);
    STGA(0, 1, t2);
    BAR8; WL0; MM8(0, 0, b0); BAR8;
    LDB8(1, 1, b1);
    STGA(1, 0, t3);
    BAR8; WL0; MM8(0, 1, b1); BAR8;
    LDA8(1, 1);
    STGB(1, 0, t3);
    BAR8; WL0; MM8(1, 1, b1); BAR8;
    STGB(1, 1, t3);
    WV6;
    BAR8; WL0; MM8(1, 0, b0); BAR8;
  }

#pragma unroll
  for (int rh = 0; rh < 2; ++rh)
#pragma unroll
    for (int ch = 0; ch < 2; ++ch)
#pragma unroll
      for (int ri = 0; ri < 4; ++ri)
#pragma unroll
        for (int ci = 0; ci < 2; ++ci)
#pragma unroll
          for (int j = 0; j < 4; ++j) {
            const int row = m0 + rh * 128 + wr * 64 + ri * 16 + lg * 4 + j;
            const int col = n0 + ch * 128 + wc * 32 + ci * 16 + lr;
            if (OUTMODE == 0)
              ((unsigned short*)Cp)[(long)row * 4096 + col] = f2bf(acc[rh][ch][ri][ci][j]);
            else
              ((float*)Cp)[(long)row * 4096 + col] = acc[rh][ch][ri][ci][j];
          }
#undef STGA
#undef STGB
#undef LDA8
#undef LDB8
#undef MM8
}

// --------------------------------------------- fused per-head RMSNorm + RoPE
__global__ __launch_bounds__(256) void normrope_kernel(unsigned short* __restrict__ X,
                                                       const float* __restrict__ wnorm,
                                                       const int* __restrict__ positions,
                                                       int hshift, int stride) {
  const int t = threadIdx.x, l = t & 63, wv = t >> 6;
  const int slice = blockIdx.x * 4 + wv;
  const int head  = slice & ((1 << hshift) - 1);
  const int row   = slice >> hshift;
  const int s     = row & (SEQ - 1);
  unsigned short* p = X + (long)row * stride + (head << 7);

  float x1 = bf2f(p[l]), x2 = bf2f(p[l + 64]);
  float ss = x1 * x1 + x2 * x2;
#pragma unroll
  for (int m = 1; m < 64; m <<= 1) ss += __shfl_xor(ss, m, 64);
  float inv = rsqrtf(ss * (1.0f / 128.0f) + 1e-6f);
  x1 *= inv * wnorm[l];
  x2 *= inv * wnorm[l + 64];

  float invf = exp2f((float)l * -0.31143075889569023f);
  float ang  = (float)positions[s] * invf;
  float sn, cs;
  sincosf(ang, &sn, &cs);
  p[l]      = f2bf(x1 * cs - x2 * sn);
  p[l + 64] = f2bf(x2 * cs + x1 * sn);
}

// ------------------------------------------------------------ flash attention
// 32x32 swapped-QK^T, LDS-staged K/V (ring-4, stage-3-ahead, counted vmcnt),
// cross-iteration pipeline: QK^T(ti+1) issued BEFORE softmax(ti) so softmax
// VALU hides under the dependent QK MFMA chain; PV(ti) closes the iteration.
// Ring-safety: stage@ti writes slot (ti+3)&3 == (ti-1)&3, whose last read
// (V[ti-1] in PV@ti-1) precedes barrier@ti for all waves; vmcnt(4) before the
// barrier keeps the newest stage in flight across it (T4).
__global__ __launch_bounds__(256, 2) void attn_kernel(const unsigned short* __restrict__ Q,
                                                      const unsigned short* __restrict__ Kb,
                                                      const unsigned short* __restrict__ Vtl,
                                                      unsigned short* __restrict__ O) {
  __shared__ unsigned short lds[32768];   // 64 KiB: K rings [0,16384), V rings [16384,32768)
  __shared__ float cl[4][32];
  const int t = threadIdx.x, l = t & 63, w = t >> 6;
  const int lq = l & 31, hi = l >> 5;
  const int blk = blockIdx.x;
  const int qb = blk & 7, h = (blk >> 3) & 31, b = blk >> 8;
  const int kv = h >> 2;                     // GQA: 4 q-heads per kv-head
  const int q0 = qb * 128 + w * 32;

  // Q as B-fragments, (1/sqrt(128))*log2(e) folded in
  const float qsc = 0.12751791438584222f;
  bf16x8 qf[8];
  const unsigned short* qrow = Q + (long)(b * SEQ + q0 + lq) * HID + h * HDIM + 8 * hi;
#pragma unroll
  for (int ks = 0; ks < 8; ++ks) {
    u16x8 raw = *(const u16x8*)(qrow + ks * 16);
    bf16x8 qv;
#pragma unroll
    for (int j = 0; j < 8; ++j) qv[j] = (__bf16)(bf2f(raw[j]) * qsc);
    qf[ks] = qv;
  }

  const unsigned short* Kg = Kb + (long)(b * SEQ) * 1024 + kv * HDIM;
  const unsigned short* Vg = Vtl + (long)(b * NKV + kv) * 32 * 4096;

  // stage: 8KB/tile each for K and V; 256 threads x 2 gload16 each.
#define STG_K(ring, ti) do { \
    _Pragma("unroll") for (int rr = 0; rr < 2; ++rr) { \
      int _row = (rr * 4 + w) * 4 + (l >> 4); \
      int _sc  = (l & 15) ^ (_row & 15); \
      gload16(Kg + (long)((ti) * 32 + _row) * 1024 + (_sc << 3), \
              lds + (ring) * 4096 + (rr * 4 + w) * 512); \
    } } while (0)
#define STG_V(ring, ti) do { \
    _Pragma("unroll") for (int rr = 0; rr < 2; ++rr) \
      gload16(Vg + (long)(ti) * 4096 + (((rr * 4 + w) * 64 + l) << 3), \
              lds + 16384 + (ring) * 4096 + (rr * 4 + w) * 512); \
    } while (0)
#define QKT(dst, ring) do { \
    const unsigned short* kb = lds + (ring) * 4096 + lq * 128; \
    bf16x8 kf[8]; \
    _Pragma("unroll") for (int ks = 0; ks < 8; ++ks) \
      kf[ks] = *(const bf16x8*)(kb + ((((ks << 1) + hi) ^ (lq & 15)) << 3)); \
    __builtin_amdgcn_s_setprio(1); \
    _Pragma("unroll") for (int ks = 0; ks < 8; ++ks) \
      dst = __builtin_amdgcn_mfma_f32_32x32x16_bf16(kf[ks], qf[ks], dst, 0, 0, 0); \
    __builtin_amdgcn_s_setprio(0); \
  } while (0)

  f32x16 acc[4] = {};
  float m = -3.0e38f, lsum = 0.f;

  // prologue: tiles 0,1,2 into rings 0,1,2 (12 DMAs); tile0 landed -> QK(0)
  STG_K(0, 0); STG_V(0, 0);
  STG_K(1, 1); STG_V(1, 1);
  STG_K(2, 2); STG_V(2, 2);
  asm volatile("s_waitcnt vmcnt(8)" ::: "memory");
  __builtin_amdgcn_s_barrier();
  __builtin_amdgcn_sched_barrier(0);

  f32x16 s_cur = {};
  QKT(s_cur, 0);

#pragma unroll 2
  for (int ti = 0; ti < 32; ++ti) {
    // drain to 4 outstanding: stage(ti+1) landed; stage(ti+2) stays in flight
    asm volatile("s_waitcnt vmcnt(4)" ::: "memory");
    __builtin_amdgcn_s_barrier();
    __builtin_amdgcn_sched_barrier(0);

    // stage tile ti+3 into ring (ti+3)&3 (== ring (ti-1)&3, last read @ti-1)
    const int rs = (ti + 3) & 3, tn = (ti + 3) & 31;
    STG_K(rs, tn); STG_V(rs, tn);

    // QK^T of NEXT tile (independent of softmax below -> scheduler interleaves)
    f32x16 s_next = {};
    QKT(s_next, (ti + 1) & 3);

    // online softmax on s_cur (tile ti)
    float t0 = fmaxf(fmaxf(s_cur[0], s_cur[1]), fmaxf(s_cur[2], s_cur[3]));
    float t1 = fmaxf(fmaxf(s_cur[4], s_cur[5]), fmaxf(s_cur[6], s_cur[7]));
    float t2 = fmaxf(fmaxf(s_cur[8], s_cur[9]), fmaxf(s_cur[10], s_cur[11]));
    float t3 = fmaxf(fmaxf(s_cur[12], s_cur[13]), fmaxf(s_cur[14], s_cur[15]));
    float rm = fmaxf(fmaxf(t0, t1), fmaxf(t2, t3));
    rm = fmaxf(rm, __shfl_xor(rm, 32, 64));

    if (__any(rm > m + 8.0f)) {        // T13 defer-max
      float mn = fmaxf(m, rm);
      float corr = exp2f(m - mn);
      m = mn;
      lsum *= corr;
      cl[w][lq] = corr;
      float cc[16];
#pragma unroll
      for (int r = 0; r < 16; ++r)
        cc[r] = cl[w][(r & 3) + 8 * (r >> 2) + 4 * hi];
#pragma unroll
      for (int db = 0; db < 4; ++db)
#pragma unroll
        for (int r = 0; r < 16; ++r) acc[db][r] *= cc[r];
    }

    float p[16];
    float ps = 0.f;
#pragma unroll
    for (int r = 0; r < 16; ++r) { p[r] = exp2f(s_cur[r] - m); ps += p[r]; }
    lsum += ps + __shfl_xor(ps, 32, 64);

    // T12: pack P into PV A-fragments
    bf16x8 pa[2];
#pragma unroll
    for (int c = 0; c < 2; ++c) {
      unsigned a0 = cvtpk_bf16(p[8 * c + 0], p[8 * c + 1]);
      unsigned b0 = cvtpk_bf16(p[8 * c + 4], p[8 * c + 5]);
      unsigned a1 = cvtpk_bf16(p[8 * c + 2], p[8 * c + 3]);
      unsigned b1 = cvtpk_bf16(p[8 * c + 6], p[8 * c + 7]);
      asm("v_permlane32_swap_b32 %0, %1" : "+v"(a0), "+v"(b0));
      asm("v_permlane32_swap_b32 %0, %1" : "+v"(a1), "+v"(b1));
      u32x4 w4 = {a0, a1, b0, b1};
      pa[c] = __builtin_bit_cast(bf16x8, w4);
    }

    // PV from V ring ti&3 (swizzled [d][k32] tile)
    __builtin_amdgcn_s_setprio(1);
#pragma unroll
    for (int db = 0; db < 4; ++db) {
      const int row = db * 32 + lq;
      const int fx  = (row ^ (row >> 2)) & 3;
      const unsigned short* vb = lds + 16384 + (ti & 3) * 4096 + row * 32;
      bf16x8 v0 = *(const bf16x8*)(vb + ((hi ^ fx) << 3));
      bf16x8 v1 = *(const bf16x8*)(vb + (((2 + hi) ^ fx) << 3));
      acc[db] = __builtin_amdgcn_mfma_f32_32x32x16_bf16(pa[0], v0, acc[db], 0, 0, 0);
      acc[db] = __builtin_amdgcn_mfma_f32_32x32x16_bf16(pa[1], v1, acc[db], 0, 0, 0);
    }
    __builtin_amdgcn_s_setprio(0);

    s_cur = s_next;
  }
#undef STG_K
#undef STG_V
#undef QKT

  float il = 1.0f / lsum;
  cl[w][lq] = il;
  float ic[16];
#pragma unroll
  for (int r = 0; r < 16; ++r)
    ic[r] = cl[w][(r & 3) + 8 * (r >> 2) + 4 * hi];
#pragma unroll
  for (int db = 0; db < 4; ++db)
#pragma unroll
    for (int r = 0; r < 16; ++r) {
      int row = (r & 3) + 8 * (r >> 2) + 4 * hi;
      O[(long)(b * SEQ + q0 + row) * HID + h * HDIM + db * 32 + lq] =
          f2bf(acc[db][r] * ic[r]);
    }
}

// ------------------------------------------------------------------- launcher
extern "C" void kernel_launch(void* const* d_in, const int* in_sizes, int n_in,
                              void* d_out, int out_size, void* d_ws, size_t ws_size,
                              hipStream_t stream) {
  (void)in_sizes; (void)n_in; (void)out_size; (void)ws_size;
  const int*   positions = (const int*)d_in[0];
  const float* hs = (const float*)d_in[1];
  const float* wq = (const float*)d_in[2];
  const float* wk = (const float*)d_in[3];
  const float* wv = (const float*)d_in[4];
  const float* wo = (const float*)d_in[5];
  const float* qw = (const float*)d_in[6];
  const float* kw = (const float*)d_in[7];

  char* ws = (char*)d_ws;                                   // 160 MB total
  unsigned short* hs_b = (unsigned short*)(ws);              // 32 MB
  unsigned short* wq_b = (unsigned short*)(ws + 33554432);   // 32 MB (reused as attn-out)
  unsigned short* wk_b = (unsigned short*)(ws + 67108864);   //  8 MB
  unsigned short* wv_b = (unsigned short*)(ws + 75497472);   //  8 MB
  unsigned short* wo_b = (unsigned short*)(ws + 83886080);   // 32 MB
  unsigned short* q_b  = (unsigned short*)(ws + 117440512);  // 32 MB
  unsigned short* k_b  = (unsigned short*)(ws + 150994944);  //  8 MB
  unsigned short* vt_b = (unsigned short*)(ws + 159383552);  //  8 MB (V tiles)
  unsigned short* ao_b = wq_b;  // wq dead after Q-proj; alias for attention out

  // fused f32 -> bf16 conversion (5 segments, one launch)
  cvt_all<<<dim3(28672), dim3(256), 0, stream>>>(hs, wq, wk, wv, wo,
                                                 hs_b, wq_b, wk_b, wv_b, wo_b);

  // projections: Q via 8-phase 256² template; K via 128²; V -> swizzled tiles
  gemm8_bt<0><<<dim3(256), dim3(512), 0, stream>>>(hs_b, wq_b, q_b);
  gemm_bt<0><<<dim3(8, 32), dim3(256), 0, stream>>>(hs_b, wk_b, k_b, 4096, 1024, 4096, 1024);
  gemm_bt<3><<<dim3(8, 32), dim3(256), 0, stream>>>(hs_b, wv_b, vt_b, 4096, 1024, 4096, 0);

  // per-head RMSNorm + RoPE (in place; K normed in k_b before attn stages it)
  normrope_kernel<<<dim3(32768), dim3(256), 0, stream>>>(q_b, qw, positions, 5, 4096);
  normrope_kernel<<<dim3(8192), dim3(256), 0, stream>>>(k_b, kw, positions, 3, 1024);

  // attention: 4b x 32h x 8 q-blocks = 1024 blocks, ring-4 pipelined K/V
  attn_kernel<<<dim3(1024), dim3(256), 0, stream>>>(q_b, k_b, vt_b, ao_b);

  // output projection -> f32 d_out (8-phase 256² template)
  gemm8_bt<1><<<dim3(256), dim3(512), 0, stream>>>(ao_b, wo_b, (float*)d_out);
}

// Round 9
// 498.735 us; speedup vs baseline: 2.0799x; 1.1404x over previous
//
#include <hip/hip_runtime.h>
#include <math.h>

// Problem constants (B=4, S=1024, HIDDEN=4096, H=32, KV=8, D=128)
#define SEQ    1024
#define BATCH  4
#define MROWS  4096          // B*S
#define HID    4096
#define NHEADS 32
#define NKV    8
#define HDIM   128

typedef __bf16 bf16x8 __attribute__((ext_vector_type(8)));
typedef float  f32x4  __attribute__((ext_vector_type(4)));
typedef float  f32x16 __attribute__((ext_vector_type(16)));
typedef unsigned short u16x8 __attribute__((ext_vector_type(8)));
typedef unsigned short u16x4 __attribute__((ext_vector_type(4)));
typedef unsigned int   u32x4 __attribute__((ext_vector_type(4)));

static __device__ __forceinline__ unsigned short f2bf(float f) {
  union { float f; unsigned u; } x; x.f = f;
  unsigned r = x.u + 0x7fffu + ((x.u >> 16) & 1u);   // RNE
  return (unsigned short)(r >> 16);
}
static __device__ __forceinline__ float bf2f(unsigned short h) {
  union { unsigned u; float f; } x; x.u = ((unsigned)h) << 16;
  return x.f;
}
static __device__ __forceinline__ unsigned cvtpk_bf16(float lo, float hi) {
  unsigned r;
  asm("v_cvt_pk_bf16_f32 %0, %1, %2" : "=v"(r) : "v"(lo), "v"(hi));
  return r;
}

// async global->LDS, 16B per lane; LDS dest is wave-uniform base + lane*16
static __device__ __forceinline__ void gload16(const unsigned short* g, unsigned short* l) {
  __builtin_amdgcn_global_load_lds(
      (const __attribute__((address_space(1))) unsigned int*)g,
      (__attribute__((address_space(3))) unsigned int*)l, 16, 0, 0);
}

// ------------------------------------------------- fused f32 -> bf16 (all 5 inputs)
__global__ __launch_bounds__(256) void cvt_all(const float* __restrict__ hs,
                                               const float* __restrict__ wq,
                                               const float* __restrict__ wk,
                                               const float* __restrict__ wv,
                                               const float* __restrict__ wo,
                                               unsigned short* __restrict__ hs_b,
                                               unsigned short* __restrict__ wq_b,
                                               unsigned short* __restrict__ wk_b,
                                               unsigned short* __restrict__ wv_b,
                                               unsigned short* __restrict__ wo_b) {
  const int bid = blockIdx.x;
  const float* in; unsigned short* out; int base;
  if (bid < 8192)       { in = hs; out = hs_b; base = 0; }
  else if (bid < 16384) { in = wq; out = wq_b; base = 8192; }
  else if (bid < 18432) { in = wk; out = wk_b; base = 16384; }
  else if (bid < 20480) { in = wv; out = wv_b; base = 18432; }
  else                  { in = wo; out = wo_b; base = 20480; }
  const int i = (bid - base) * 256 + threadIdx.x;
  f32x4 a = ((const f32x4*)in)[2 * i];
  f32x4 b = ((const f32x4*)in)[2 * i + 1];
  u16x8 o;
  o[0] = f2bf(a[0]); o[1] = f2bf(a[1]); o[2] = f2bf(a[2]); o[3] = f2bf(a[3]);
  o[4] = f2bf(b[0]); o[5] = f2bf(b[1]); o[6] = f2bf(b[2]); o[7] = f2bf(b[3]);
  ((u16x8*)out)[i] = o;
}

// ---------------------------------------- fused K-proj + V-proj (128² tile GEMM)
// z=0: K = hs·wk^T -> bf16 [4096][1024]
// z=1: V = hs·wv^T -> swizzled V tiles [b][kv][kt32][d128][k32]
//      (elem (d,k) at d*32 + ((k>>3)^((d^(d>>2))&3))*8 + (k&7))
// 512 blocks total -> 2 blocks/CU -> 8 waves/CU (vs 4 when launched separately).
__global__ __launch_bounds__(256) void gemm_kv(const unsigned short* __restrict__ A,
                                               const unsigned short* __restrict__ Bk,
                                               const unsigned short* __restrict__ Bv,
                                               unsigned short* __restrict__ Ck,
                                               unsigned short* __restrict__ Cv) {
  __shared__ unsigned short As[4096];   // [128][32]
  __shared__ unsigned short Bs[4096];
  const int t  = threadIdx.x;
  const int l  = t & 63, w = t >> 6;
  const int wr = w >> 1, wc = w & 1;
  const int lr = l & 15, lg = l >> 4;
  const int m0 = blockIdx.y * 128, n0 = blockIdx.x * 128;
  const int z  = blockIdx.z;
  const unsigned short* B = z ? Bv : Bk;
  const int K = 4096;

  const int srow = t >> 2;
  const int skg  = (t & 3) ^ (srow & 3);
  const unsigned short* ga0 = A + (long)(m0 + srow) * K + skg * 8;
  const unsigned short* ga1 = ga0 + 64L * K;
  const unsigned short* gb0 = B + (long)(n0 + srow) * K + skg * 8;
  const unsigned short* gb1 = gb0 + 64L * K;

  int aro[4], bro[4];
#pragma unroll
  for (int i = 0; i < 4; ++i) {
    aro[i] = (wr * 64 + i * 16 + lr) * 32 + ((lg ^ (lr & 3)) * 8);
    bro[i] = (wc * 64 + i * 16 + lr) * 32 + ((lg ^ (lr & 3)) * 8);
  }

  f32x4 acc[4][4] = {};
  for (int k0 = 0; k0 < K; k0 += 32) {
    if (k0) __syncthreads();
    gload16(ga0 + k0, As + (w << 9));
    gload16(ga1 + k0, As + 2048 + (w << 9));
    gload16(gb0 + k0, Bs + (w << 9));
    gload16(gb1 + k0, Bs + 2048 + (w << 9));
    __syncthreads();
    bf16x8 af[4], bfv[4];
#pragma unroll
    for (int i = 0; i < 4; ++i) af[i]  = *(const bf16x8*)(As + aro[i]);
#pragma unroll
    for (int i = 0; i < 4; ++i) bfv[i] = *(const bf16x8*)(Bs + bro[i]);
#pragma unroll
    for (int mi = 0; mi < 4; ++mi)
#pragma unroll
      for (int ni = 0; ni < 4; ++ni)
        acc[mi][ni] = __builtin_amdgcn_mfma_f32_16x16x32_bf16(af[mi], bfv[ni],
                                                              acc[mi][ni], 0, 0, 0);
  }

  const int r0 = m0 + wr * 64 + lg * 4;
  const int c0 = n0 + wc * 64 + lr;
  if (z == 0) {
#pragma unroll
    for (int mi = 0; mi < 4; ++mi)
#pragma unroll
      for (int ni = 0; ni < 4; ++ni)
#pragma unroll
        for (int j = 0; j < 4; ++j)
          Ck[(long)(r0 + mi * 16 + j) * 1024 + (c0 + ni * 16)] = f2bf(acc[mi][ni][j]);
  } else {
#pragma unroll
    for (int mi = 0; mi < 4; ++mi)
#pragma unroll
      for (int ni = 0; ni < 4; ++ni) {
        const int s_g   = r0 + mi * 16;            // 4 consecutive s (j=0..3)
        const int d_g   = c0 + ni * 16;
        const int bb    = s_g >> 10;
        const int s_loc = s_g & 1023;
        const int kt_i  = s_loc >> 5;
        const int k_loc = s_loc & 31;              // ≡0 mod 4 -> same 8B slot
        const int kvh   = d_g >> 7;
        const int d_loc = d_g & 127;
        const int fxor  = (d_loc ^ (d_loc >> 2)) & 3;
        const long addr = ((long)((bb * NKV + kvh) * 32 + kt_i)) * 4096 +
                          d_loc * 32 + (((k_loc >> 3) ^ fxor) << 3) + (k_loc & 7);
        u16x4 v;
#pragma unroll
        for (int j = 0; j < 4; ++j) v[j] = f2bf(acc[mi][ni][j]);
        *(u16x4*)(Cv + addr) = v;
      }
  }
}

// ---------------------------------------------- 256² 8-phase GEMM (T2+T3+T4+T5)
// (unchanged — verified: ~120 µs per 4096³, MfmaUtil 50.6%, pass)
#define BAR8 __builtin_amdgcn_s_barrier()
#define WL0  do { asm volatile("s_waitcnt lgkmcnt(0)" ::: "memory"); \
                  __builtin_amdgcn_sched_barrier(0); } while (0)
#define WV6  asm volatile("s_waitcnt vmcnt(6)" ::: "memory")

template <int OUTMODE>
__global__ __launch_bounds__(512, 2) void gemm8_bt(const unsigned short* __restrict__ A,
                                                   const unsigned short* __restrict__ B,
                                                   void* __restrict__ Cp) {
  __shared__ unsigned short lds[65536];        // 128 KiB
  const int t = threadIdx.x, l = t & 63, w = t >> 6;
  const int wr = w >> 2, wc = w & 3;
  const int lr = l & 15, lg = l >> 4;
  const int bid = blockIdx.x;
  const int swz = (bid & 7) * 32 + (bid >> 3);  // XCD swizzle (256 % 8 == 0)
  const int m0 = (swz >> 4) << 8, n0 = (swz & 15) << 8;
  const long K = 4096;

  const int rc = l >> 3;
  const int ce = ((l & 7) ^ rc) << 3;

#define STGA(d, h, tt) do { \
    const unsigned short* _s = A + (long)(m0 + (h)*128 + w*8 + rc) * K + (long)(tt)*64 + ce; \
    gload16(_s,            lds + ((d)*2+(h))*8192 + w*512); \
    gload16(_s + 64L * K,  lds + ((d)*2+(h))*8192 + (8 + w)*512); \
  } while (0)
#define STGB(d, h, tt) do { \
    const unsigned short* _s = B + (long)(n0 + (h)*128 + w*8 + rc) * K + (long)(tt)*64 + ce; \
    gload16(_s,            lds + 32768 + ((d)*2+(h))*8192 + w*512); \
    gload16(_s + 64L * K,  lds + 32768 + ((d)*2+(h))*8192 + (8 + w)*512); \
  } while (0)
#define LDA8(d, rh) do { \
    _Pragma("unroll") for (int ri = 0; ri < 4; ++ri) \
    _Pragma("unroll") for (int kk = 0; kk < 2; ++kk) { \
      int r  = wr*64 + ri*16 + lr; \
      int cb = (kk*64 + lg*16) ^ ((l & 7) << 4); \
      a[ri][kk] = *(const bf16x8*)(lds + ((d)*2+(rh))*8192 + r*64 + (cb >> 1)); \
    } } while (0)
#define LDB8(d, ch, barr) do { \
    _Pragma("unroll") for (int ci = 0; ci < 2; ++ci) \
    _Pragma("unroll") for (int kk = 0; kk < 2; ++kk) { \
      int r  = wc*32 + ci*16 + lr; \
      int cb = (kk*64 + lg*16) ^ ((l & 7) << 4); \
      barr[ci][kk] = *(const bf16x8*)(lds + 32768 + ((d)*2+(ch))*8192 + r*64 + (cb >> 1)); \
    } } while (0)
#define MM8(rh, ch, barr) do { \
    __builtin_amdgcn_s_setprio(1); \
    _Pragma("unroll") for (int kk = 0; kk < 2; ++kk) \
    _Pragma("unroll") for (int ri = 0; ri < 4; ++ri) \
    _Pragma("unroll") for (int ci = 0; ci < 2; ++ci) \
      acc[rh][ch][ri][ci] = __builtin_amdgcn_mfma_f32_16x16x32_bf16( \
          a[ri][kk], barr[ci][kk], acc[rh][ch][ri][ci], 0, 0, 0); \
    __builtin_amdgcn_s_setprio(0); \
  } while (0)

  f32x4 acc[2][2][4][2] = {};
  bf16x8 a[4][2], b0[2][2], b1[2][2];

  STGA(0, 0, 0); STGB(0, 0, 0); STGB(0, 1, 0); STGA(0, 1, 0);
  STGA(1, 0, 1); STGB(1, 0, 1); STGB(1, 1, 1);
  WV6;
  BAR8;

  for (int i = 0; i < 32; ++i) {
    const int t1 = 2 * i + 1, t2 = (2 * i + 2) & 63, t3 = (2 * i + 3) & 63;
    LDA8(0, 0); LDB8(0, 0, b0);
    STGA(1, 1, t1);
    BAR8; WL0; MM8(0, 0, b0); BAR8;
    LDB8(0, 1, b1);
    STGA(0, 0, t2);
    BAR8; WL0; MM8(0, 1, b1); BAR8;
    LDA8(0, 1);
    STGB(0, 0, t2);
    BAR8; WL0; MM8(1, 1, b1); BAR8;
    STGB(0, 1, t2);
    WV6;
    BAR8; WL0; MM8(1, 0, b0); BAR8;
    LDA8(1, 0); LDB8(1, 0, b0);
    STGA(0, 1, t2);
    BAR8; WL0; MM8(0, 0, b0); BAR8;
    LDB8(1, 1, b1);
    STGA(1, 0, t3);
    BAR8; WL0; MM8(0, 1, b1); BAR8;
    LDA8(1, 1);
    STGB(1, 0, t3);
    BAR8; WL0; MM8(1, 1, b1); BAR8;
    STGB(1, 1, t3);
    WV6;
    BAR8; WL0; MM8(1, 0, b0); BAR8;
  }

#pragma unroll
  for (int rh = 0; rh < 2; ++rh)
#pragma unroll
    for (int ch = 0; ch < 2; ++ch)
#pragma unroll
      for (int ri = 0; ri < 4; ++ri)
#pragma unroll
        for (int ci = 0; ci < 2; ++ci)
#pragma unroll
          for (int j = 0; j < 4; ++j) {
            const int row = m0 + rh * 128 + wr * 64 + ri * 16 + lg * 4 + j;
            const int col = n0 + ch * 128 + wc * 32 + ci * 16 + lr;
            if (OUTMODE == 0)
              ((unsigned short*)Cp)[(long)row * 4096 + col] = f2bf(acc[rh][ch][ri][ci][j]);
            else
              ((float*)Cp)[(long)row * 4096 + col] = acc[rh][ch][ri][ci][j];
          }
#undef STGA
#undef STGB
#undef LDA8
#undef LDB8
#undef MM8
}

// --------------------------------- fused per-head RMSNorm + RoPE (Q and K in one)
// bid < 32768: Q slices (hshift 5, stride 4096); else K slices (hshift 3, 1024)
__global__ __launch_bounds__(256) void normrope_all(unsigned short* __restrict__ Qx,
                                                    unsigned short* __restrict__ Kx,
                                                    const float* __restrict__ qwn,
                                                    const float* __restrict__ kwn,
                                                    const int* __restrict__ positions) {
  const int t = threadIdx.x, l = t & 63, wv = t >> 6;
  const int bid = blockIdx.x;
  unsigned short* X; const float* wnorm; int hshift, stride, slice;
  if (bid < 32768) { X = Qx; wnorm = qwn; hshift = 5; stride = 4096; slice = bid * 4 + wv; }
  else             { X = Kx; wnorm = kwn; hshift = 3; stride = 1024; slice = (bid - 32768) * 4 + wv; }
  const int head  = slice & ((1 << hshift) - 1);
  const int row   = slice >> hshift;
  const int s     = row & (SEQ - 1);
  unsigned short* p = X + (long)row * stride + (head << 7);

  float x1 = bf2f(p[l]), x2 = bf2f(p[l + 64]);
  float ss = x1 * x1 + x2 * x2;
#pragma unroll
  for (int m = 1; m < 64; m <<= 1) ss += __shfl_xor(ss, m, 64);
  float inv = rsqrtf(ss * (1.0f / 128.0f) + 1e-6f);
  x1 *= inv * wnorm[l];
  x2 *= inv * wnorm[l + 64];

  float invf = exp2f((float)l * -0.31143075889569023f);
  float ang  = (float)positions[s] * invf;
  float sn, cs;
  sincosf(ang, &sn, &cs);
  p[l]      = f2bf(x1 * cs - x2 * sn);
  p[l + 64] = f2bf(x2 * cs + x1 * sn);
}

// ------------------------------------------------------------ flash attention
// (structure unchanged from R8 — ring-4 pipelined K/V, cross-iter QK^T; passed)
// NEW: T1 XCD-aware block swizzle — all 32 blocks sharing one (b,kv) K/V set
// land on one XCD (1024 % 8 == 0, bijective).
__global__ __launch_bounds__(256, 2) void attn_kernel(const unsigned short* __restrict__ Q,
                                                      const unsigned short* __restrict__ Kb,
                                                      const unsigned short* __restrict__ Vtl,
                                                      unsigned short* __restrict__ O) {
  __shared__ unsigned short lds[32768];   // 64 KiB: K rings [0,16384), V rings [16384,32768)
  __shared__ float cl[4][32];
  const int t = threadIdx.x, l = t & 63, w = t >> 6;
  const int lq = l & 31, hi = l >> 5;
  const int orig = blockIdx.x;
  const int blk = (orig & 7) * 128 + (orig >> 3);   // XCD swizzle
  const int qb = blk & 7, h = (blk >> 3) & 31, b = blk >> 8;
  const int kv = h >> 2;                     // GQA: 4 q-heads per kv-head
  const int q0 = qb * 128 + w * 32;

  // Q as B-fragments, (1/sqrt(128))*log2(e) folded in
  const float qsc = 0.12751791438584222f;
  bf16x8 qf[8];
  const unsigned short* qrow = Q + (long)(b * SEQ + q0 + lq) * HID + h * HDIM + 8 * hi;
#pragma unroll
  for (int ks = 0; ks < 8; ++ks) {
    u16x8 raw = *(const u16x8*)(qrow + ks * 16);
    bf16x8 qv;
#pragma unroll
    for (int j = 0; j < 8; ++j) qv[j] = (__bf16)(bf2f(raw[j]) * qsc);
    qf[ks] = qv;
  }

  const unsigned short* Kg = Kb + (long)(b * SEQ) * 1024 + kv * HDIM;
  const unsigned short* Vg = Vtl + (long)(b * NKV + kv) * 32 * 4096;

#define STG_K(ring, ti) do { \
    _Pragma("unroll") for (int rr = 0; rr < 2; ++rr) { \
      int _row = (rr * 4 + w) * 4 + (l >> 4); \
      int _sc  = (l & 15) ^ (_row & 15); \
      gload16(Kg + (long)((ti) * 32 + _row) * 1024 + (_sc << 3), \
              lds + (ring) * 4096 + (rr * 4 + w) * 512); \
    } } while (0)
#define STG_V(ring, ti) do { \
    _Pragma("unroll") for (int rr = 0; rr < 2; ++rr) \
      gload16(Vg + (long)(ti) * 4096 + (((rr * 4 + w) * 64 + l) << 3), \
              lds + 16384 + (ring) * 4096 + (rr * 4 + w) * 512); \
    } while (0)
#define QKT(dst, ring) do { \
    const unsigned short* kb = lds + (ring) * 4096 + lq * 128; \
    bf16x8 kf[8]; \
    _Pragma("unroll") for (int ks = 0; ks < 8; ++ks) \
      kf[ks] = *(const bf16x8*)(kb + ((((ks << 1) + hi) ^ (lq & 15)) << 3)); \
    __builtin_amdgcn_s_setprio(1); \
    _Pragma("unroll") for (int ks = 0; ks < 8; ++ks) \
      dst = __builtin_amdgcn_mfma_f32_32x32x16_bf16(kf[ks], qf[ks], dst, 0, 0, 0); \
    __builtin_amdgcn_s_setprio(0); \
  } while (0)

  f32x16 acc[4] = {};
  float m = -3.0e38f, lsum = 0.f;

  // prologue: tiles 0,1,2 into rings 0,1,2; tile0 landed -> QK(0)
  STG_K(0, 0); STG_V(0, 0);
  STG_K(1, 1); STG_V(1, 1);
  STG_K(2, 2); STG_V(2, 2);
  asm volatile("s_waitcnt vmcnt(8)" ::: "memory");
  __builtin_amdgcn_s_barrier();
  __builtin_amdgcn_sched_barrier(0);

  f32x16 s_cur = {};
  QKT(s_cur, 0);

#pragma unroll 2
  for (int ti = 0; ti < 32; ++ti) {
    asm volatile("s_waitcnt vmcnt(4)" ::: "memory");
    __builtin_amdgcn_s_barrier();
    __builtin_amdgcn_sched_barrier(0);

    const int rs = (ti + 3) & 3, tn = (ti + 3) & 31;
    STG_K(rs, tn); STG_V(rs, tn);

    // QK^T of NEXT tile (independent of softmax below)
    f32x16 s_next = {};
    QKT(s_next, (ti + 1) & 3);

    // online softmax on s_cur (tile ti)
    float t0 = fmaxf(fmaxf(s_cur[0], s_cur[1]), fmaxf(s_cur[2], s_cur[3]));
    float t1 = fmaxf(fmaxf(s_cur[4], s_cur[5]), fmaxf(s_cur[6], s_cur[7]));
    float t2 = fmaxf(fmaxf(s_cur[8], s_cur[9]), fmaxf(s_cur[10], s_cur[11]));
    float t3 = fmaxf(fmaxf(s_cur[12], s_cur[13]), fmaxf(s_cur[14], s_cur[15]));
    float rm = fmaxf(fmaxf(t0, t1), fmaxf(t2, t3));
    rm = fmaxf(rm, __shfl_xor(rm, 32, 64));

    if (__any(rm > m + 8.0f)) {        // T13 defer-max
      float mn = fmaxf(m, rm);
      float corr = exp2f(m - mn);
      m = mn;
      lsum *= corr;
      cl[w][lq] = corr;
      float cc[16];
#pragma unroll
      for (int r = 0; r < 16; ++r)
        cc[r] = cl[w][(r & 3) + 8 * (r >> 2) + 4 * hi];
#pragma unroll
      for (int db = 0; db < 4; ++db)
#pragma unroll
        for (int r = 0; r < 16; ++r) acc[db][r] *= cc[r];
    }

    float p[16];
    float ps = 0.f;
#pragma unroll
    for (int r = 0; r < 16; ++r) { p[r] = exp2f(s_cur[r] - m); ps += p[r]; }
    lsum += ps + __shfl_xor(ps, 32, 64);

    // T12: pack P into PV A-fragments
    bf16x8 pa[2];
#pragma unroll
    for (int c = 0; c < 2; ++c) {
      unsigned a0 = cvtpk_bf16(p[8 * c + 0], p[8 * c + 1]);
      unsigned b0 = cvtpk_bf16(p[8 * c + 4], p[8 * c + 5]);
      unsigned a1 = cvtpk_bf16(p[8 * c + 2], p[8 * c + 3]);
      unsigned b1 = cvtpk_bf16(p[8 * c + 6], p[8 * c + 7]);
      asm("v_permlane32_swap_b32 %0, %1" : "+v"(a0), "+v"(b0));
      asm("v_permlane32_swap_b32 %0, %1" : "+v"(a1), "+v"(b1));
      u32x4 w4 = {a0, a1, b0, b1};
      pa[c] = __builtin_bit_cast(bf16x8, w4);
    }

    // PV from V ring ti&3 (swizzled [d][k32] tile)
    __builtin_amdgcn_s_setprio(1);
#pragma unroll
    for (int db = 0; db < 4; ++db) {
      const int row = db * 32 + lq;
      const int fx  = (row ^ (row >> 2)) & 3;
      const unsigned short* vb = lds + 16384 + (ti & 3) * 4096 + row * 32;
      bf16x8 v0 = *(const bf16x8*)(vb + ((hi ^ fx) << 3));
      bf16x8 v1 = *(const bf16x8*)(vb + (((2 + hi) ^ fx) << 3));
      acc[db] = __builtin_amdgcn_mfma_f32_32x32x16_bf16(pa[0], v0, acc[db], 0, 0, 0);
      acc[db] = __builtin_amdgcn_mfma_f32_32x32x16_bf16(pa[1], v1, acc[db], 0, 0, 0);
    }
    __builtin_amdgcn_s_setprio(0);

    s_cur = s_next;
  }
#undef STG_K
#undef STG_V
#undef QKT

  float il = 1.0f / lsum;
  cl[w][lq] = il;
  float ic[16];
#pragma unroll
  for (int r = 0; r < 16; ++r)
    ic[r] = cl[w][(r & 3) + 8 * (r >> 2) + 4 * hi];
#pragma unroll
  for (int db = 0; db < 4; ++db)
#pragma unroll
    for (int r = 0; r < 16; ++r) {
      int row = (r & 3) + 8 * (r >> 2) + 4 * hi;
      O[(long)(b * SEQ + q0 + row) * HID + h * HDIM + db * 32 + lq] =
          f2bf(acc[db][r] * ic[r]);
    }
}

// ------------------------------------------------------------------- launcher
extern "C" void kernel_launch(void* const* d_in, const int* in_sizes, int n_in,
                              void* d_out, int out_size, void* d_ws, size_t ws_size,
                              hipStream_t stream) {
  (void)in_sizes; (void)n_in; (void)out_size; (void)ws_size;
  const int*   positions = (const int*)d_in[0];
  const float* hs = (const float*)d_in[1];
  const float* wq = (const float*)d_in[2];
  const float* wk = (const float*)d_in[3];
  const float* wv = (const float*)d_in[4];
  const float* wo = (const float*)d_in[5];
  const float* qw = (const float*)d_in[6];
  const float* kw = (const float*)d_in[7];

  char* ws = (char*)d_ws;                                   // 160 MB total
  unsigned short* hs_b = (unsigned short*)(ws);              // 32 MB
  unsigned short* wq_b = (unsigned short*)(ws + 33554432);   // 32 MB (reused as attn-out)
  unsigned short* wk_b = (unsigned short*)(ws + 67108864);   //  8 MB
  unsigned short* wv_b = (unsigned short*)(ws + 75497472);   //  8 MB
  unsigned short* wo_b = (unsigned short*)(ws + 83886080);   // 32 MB
  unsigned short* q_b  = (unsigned short*)(ws + 117440512);  // 32 MB
  unsigned short* k_b  = (unsigned short*)(ws + 150994944);  //  8 MB
  unsigned short* vt_b = (unsigned short*)(ws + 159383552);  //  8 MB (V tiles)
  unsigned short* ao_b = wq_b;  // wq dead after Q-proj; alias for attention out

  // fused f32 -> bf16 conversion (5 segments, one launch)
  cvt_all<<<dim3(28672), dim3(256), 0, stream>>>(hs, wq, wk, wv, wo,
                                                 hs_b, wq_b, wk_b, wv_b, wo_b);

  // Q-proj (8-phase 256²) then fused K+V proj (z-indexed, 2 blocks/CU)
  gemm8_bt<0><<<dim3(256), dim3(512), 0, stream>>>(hs_b, wq_b, q_b);
  gemm_kv<<<dim3(8, 32, 2), dim3(256), 0, stream>>>(hs_b, wk_b, wv_b, k_b, vt_b);

  // fused per-head RMSNorm + RoPE for Q and K (one launch)
  normrope_all<<<dim3(40960), dim3(256), 0, stream>>>(q_b, k_b, qw, kw, positions);

  // attention: ring-4 pipelined K/V, XCD-swizzled blocks
  attn_kernel<<<dim3(1024), dim3(256), 0, stream>>>(q_b, k_b, vt_b, ao_b);

  // output projection -> f32 d_out (8-phase 256² template)
  gemm8_bt<1><<<dim3(256), dim3(512), 0, stream>>>(ao_b, wo_b, (float*)d_out);
}